// Round 1
// baseline (1046.923 us; speedup 1.0000x reference)
//
#include <hip/hip_runtime.h>

#define BB 16
#define NNN 1024
#define CC 768
#define HH 12
#define DD 64
#define HIDN 3072
#define ROWS (BB*NNN)   // 16384

typedef _Float16 half8 __attribute__((ext_vector_type(8)));
typedef _Float16 half4 __attribute__((ext_vector_type(4)));
typedef float floatx4 __attribute__((ext_vector_type(4)));

// ---------------- weight fp32 -> fp16 convert ----------------
__global__ void cvt_kernel(const float* __restrict__ src, _Float16* __restrict__ dst, int n4) {
    int i = blockIdx.x * blockDim.x + threadIdx.x;
    if (i < n4) {
        floatx4 v = ((const floatx4*)src)[i];
        half4 h;
        h[0] = (_Float16)v[0]; h[1] = (_Float16)v[1];
        h[2] = (_Float16)v[2]; h[3] = (_Float16)v[3];
        ((half4*)dst)[i] = h;
    }
}

// ---------------- LayerNorm (row of 768), fp32 in -> fp16 out ----------------
__global__ __launch_bounds__(256) void ln_kernel(const float* __restrict__ x,
                                                 const float* __restrict__ g,
                                                 const float* __restrict__ b,
                                                 _Float16* __restrict__ out) {
    int row = blockIdx.x;
    int t = threadIdx.x;
    const float* xr = x + (size_t)row * CC;
    float v0 = xr[t], v1 = xr[t + 256], v2 = xr[t + 512];
    float s = v0 + v1 + v2;
    float q = v0 * v0 + v1 * v1 + v2 * v2;
    #pragma unroll
    for (int m = 1; m < 64; m <<= 1) {
        s += __shfl_xor(s, m, 64);
        q += __shfl_xor(q, m, 64);
    }
    __shared__ float red[8];
    int wv = t >> 6, lane = t & 63;
    if (lane == 0) { red[wv] = s; red[wv + 4] = q; }
    __syncthreads();
    s = red[0] + red[1] + red[2] + red[3];
    q = red[4] + red[5] + red[6] + red[7];
    float mean = s * (1.0f / CC);
    float var = q * (1.0f / CC) - mean * mean;
    float rs = rsqrtf(var + 1e-5f);
    _Float16* orow = out + (size_t)row * CC;
    orow[t]       = (_Float16)((v0 - mean) * rs * g[t]       + b[t]);
    orow[t + 256] = (_Float16)((v1 - mean) * rs * g[t + 256] + b[t + 256]);
    orow[t + 512] = (_Float16)((v2 - mean) * rs * g[t + 512] + b[t + 512]);
}

// ---------------- MFMA GEMM: C[M,N] = A[M,K] @ W[N,K]^T + bias ----------------
// MODE 0: out fp16 = acc + bias                      (QKV)
// MODE 1: out fp16 = fmask * gelu(acc + bias)        (MLP1; fmask = gate>0)
// MODE 2: out fp32 = res + acc + bias                (proj / MLP2 residual)
template <int MODE>
__global__ __launch_bounds__(256) void gemm_kernel(
    const _Float16* __restrict__ A,
    const _Float16* __restrict__ W,
    const float* __restrict__ bias,
    const float* __restrict__ res,
    const float* __restrict__ gate,
    void* __restrict__ outp,
    int M, int N, int K)
{
    __shared__ _Float16 As[128][40];  // 40 = 32 + 8 pad (80B row stride, 16B aligned)
    __shared__ _Float16 Bs[128][40];
    int t = threadIdx.x;
    int m0 = blockIdx.y * 128, n0 = blockIdx.x * 128;
    int lane = t & 63, wv = t >> 6;
    int wm = (wv >> 1) * 64, wn = (wv & 1) * 64;
    int lrow = lane & 15, quad = lane >> 4;

    floatx4 acc[4][4];
    #pragma unroll
    for (int i = 0; i < 4; i++)
        #pragma unroll
        for (int j = 0; j < 4; j++)
            acc[i][j] = (floatx4){0.f, 0.f, 0.f, 0.f};

    int srow = t >> 1;           // 0..127
    int scol = (t & 1) * 16;     // 0 or 16
    const _Float16* ag = A + (size_t)(m0 + srow) * K + scol;
    const _Float16* bg = W + (size_t)(n0 + srow) * K + scol;

    for (int k0 = 0; k0 < K; k0 += 32) {
        half8 a0 = *(const half8*)(ag + k0);
        half8 a1 = *(const half8*)(ag + k0 + 8);
        half8 b0 = *(const half8*)(bg + k0);
        half8 b1 = *(const half8*)(bg + k0 + 8);
        __syncthreads();
        *(half8*)&As[srow][scol]     = a0;
        *(half8*)&As[srow][scol + 8] = a1;
        *(half8*)&Bs[srow][scol]     = b0;
        *(half8*)&Bs[srow][scol + 8] = b1;
        __syncthreads();
        half8 af[4], bf[4];
        #pragma unroll
        for (int i = 0; i < 4; i++) af[i] = *(const half8*)&As[wm + i * 16 + lrow][quad * 8];
        #pragma unroll
        for (int j = 0; j < 4; j++) bf[j] = *(const half8*)&Bs[wn + j * 16 + lrow][quad * 8];
        #pragma unroll
        for (int i = 0; i < 4; i++)
            #pragma unroll
            for (int j = 0; j < 4; j++)
                acc[i][j] = __builtin_amdgcn_mfma_f32_16x16x32_f16(af[i], bf[j], acc[i][j], 0, 0, 0);
    }

    // epilogue: C row = quad*4 + r (M side), col = lrow (N side)  [verified m89/m91 layout]
    #pragma unroll
    for (int i = 0; i < 4; i++) {
        #pragma unroll
        for (int j = 0; j < 4; j++) {
            int gn = n0 + wn + j * 16 + lrow;
            float bs = bias[gn];
            #pragma unroll
            for (int r = 0; r < 4; r++) {
                int gm = m0 + wm + i * 16 + quad * 4 + r;
                float v = acc[i][j][r] + bs;
                size_t idx = (size_t)gm * N + gn;
                if (MODE == 0) {
                    ((_Float16*)outp)[idx] = (_Float16)v;
                } else if (MODE == 1) {
                    float vv = (gate[gn] > 0.0f) ? 0.5f * v * (1.0f + erff(v * 0.70710678118f)) : 0.0f;
                    ((_Float16*)outp)[idx] = (_Float16)vv;
                } else {
                    ((float*)outp)[idx] = res[idx] + v;
                }
            }
        }
    }
}

// ---------------- Flash attention (vector fp32, scores in registers) ----------------
// Block: 256 thr = 16x16 (ty,tx). One block per (b, h, 64-row q tile).
// Thread owns S rows {ty+16i}, S cols {tx+16j}; O cols d = tx*4+dd.
__global__ __launch_bounds__(256) void attn_kernel(
    const _Float16* __restrict__ Q,
    const _Float16* __restrict__ Kp,
    const _Float16* __restrict__ Vp,
    const float* __restrict__ gate_h,
    _Float16* __restrict__ Y)
{
    int qt = blockIdx.x;   // 0..15
    int h  = blockIdx.y;   // 0..11
    int b  = blockIdx.z;   // 0..15
    int t = threadIdx.x;
    int tx = t & 15, ty = t >> 4;
    int q0 = qt * 64;
    size_t base = ((size_t)b * NNN) * CC + (size_t)h * DD;

    if (gate_h[h] <= 0.0f) {   // masked head: y*hm == 0 exactly
        #pragma unroll
        for (int i = 0; i < 4; i++) {
            int r = q0 + ty + 16 * i;
            half4 z = (half4){(_Float16)0.f, (_Float16)0.f, (_Float16)0.f, (_Float16)0.f};
            *(half4*)&Y[base + (size_t)r * CC + tx * 4] = z;
        }
        return;
    }

    __shared__ float Qs[64][68];   // stride 68: 272B rows, 16B aligned, conflict-friendly
    __shared__ float Ks[64][68];
    __shared__ float Vs[64][64];

    {   // stage Q tile (pre-scaled by D^-0.5 = 0.125)
        int qr = t >> 2, dblk = (t & 3) * 16;
        const _Float16* src = Q + base + (size_t)(q0 + qr) * CC + dblk;
        half8 h0 = *(const half8*)src;
        half8 h1 = *(const half8*)(src + 8);
        #pragma unroll
        for (int e = 0; e < 8; e++) Qs[qr][dblk + e]     = (float)h0[e] * 0.125f;
        #pragma unroll
        for (int e = 0; e < 8; e++) Qs[qr][dblk + 8 + e] = (float)h1[e] * 0.125f;
    }

    float O[4][4];
    float m[4], l[4];
    #pragma unroll
    for (int i = 0; i < 4; i++) {
        m[i] = -1e30f; l[i] = 0.0f;
        #pragma unroll
        for (int d = 0; d < 4; d++) O[i][d] = 0.0f;
    }

    int lane = t & 63;
    int rbase = lane & 48;   // 16-lane row-group base within wave

    for (int kt = 0; kt < 16; ++kt) {
        int k0 = kt * 64;
        __syncthreads();   // previous iteration's readers done before restaging
        {
            int kr = t >> 2, dblk = (t & 3) * 16;
            const _Float16* ksrc = Kp + base + (size_t)(k0 + kr) * CC + dblk;
            const _Float16* vsrc = Vp + base + (size_t)(k0 + kr) * CC + dblk;
            half8 kh0 = *(const half8*)ksrc;
            half8 kh1 = *(const half8*)(ksrc + 8);
            half8 vh0 = *(const half8*)vsrc;
            half8 vh1 = *(const half8*)(vsrc + 8);
            #pragma unroll
            for (int e = 0; e < 8; e++) {
                Ks[kr][dblk + e]     = (float)kh0[e];
                Ks[kr][dblk + 8 + e] = (float)kh1[e];
                Vs[kr][dblk + e]     = (float)vh0[e];
                Vs[kr][dblk + 8 + e] = (float)vh1[e];
            }
        }
        __syncthreads();

        // S = (Q*scale) K^T, 4x4 per thread, float4 over d
        float s[4][4];
        #pragma unroll
        for (int i = 0; i < 4; i++)
            #pragma unroll
            for (int j = 0; j < 4; j++) s[i][j] = 0.0f;

        for (int dstep = 0; dstep < 16; ++dstep) {
            floatx4 qa[4], kb[4];
            #pragma unroll
            for (int i = 0; i < 4; i++) qa[i] = *(const floatx4*)&Qs[ty + 16 * i][dstep * 4];
            #pragma unroll
            for (int j = 0; j < 4; j++) kb[j] = *(const floatx4*)&Ks[tx + 16 * j][dstep * 4];
            #pragma unroll
            for (int i = 0; i < 4; i++)
                #pragma unroll
                for (int j = 0; j < 4; j++)
                    #pragma unroll
                    for (int d = 0; d < 4; d++)
                        s[i][j] += qa[i][d] * kb[j][d];
        }

        // online softmax (row reductions via 16-lane shuffles)
        float alpha[4];
        #pragma unroll
        for (int i = 0; i < 4; i++) {
            float mx = fmaxf(fmaxf(s[i][0], s[i][1]), fmaxf(s[i][2], s[i][3]));
            mx = fmaxf(mx, __shfl_xor(mx, 1, 64));
            mx = fmaxf(mx, __shfl_xor(mx, 2, 64));
            mx = fmaxf(mx, __shfl_xor(mx, 4, 64));
            mx = fmaxf(mx, __shfl_xor(mx, 8, 64));
            float mnew = fmaxf(m[i], mx);
            alpha[i] = __expf(m[i] - mnew);
            m[i] = mnew;
            float ps = 0.0f;
            #pragma unroll
            for (int j = 0; j < 4; j++) { s[i][j] = __expf(s[i][j] - mnew); ps += s[i][j]; }
            ps += __shfl_xor(ps, 1, 64);
            ps += __shfl_xor(ps, 2, 64);
            ps += __shfl_xor(ps, 4, 64);
            ps += __shfl_xor(ps, 8, 64);
            l[i] = l[i] * alpha[i] + ps;
            #pragma unroll
            for (int d = 0; d < 4; d++) O[i][d] *= alpha[i];
        }

        // O += P @ V  (P broadcast via shuffle; V row broadcast from LDS)
        #pragma unroll
        for (int jj = 0; jj < 4; jj++) {
            for (int sl = 0; sl < 16; sl++) {
                int c = jj * 16 + sl;
                floatx4 v4 = *(const floatx4*)&Vs[c][tx * 4];
                float p0 = __shfl(s[0][jj], rbase + sl, 64);
                float p1 = __shfl(s[1][jj], rbase + sl, 64);
                float p2 = __shfl(s[2][jj], rbase + sl, 64);
                float p3 = __shfl(s[3][jj], rbase + sl, 64);
                #pragma unroll
                for (int d = 0; d < 4; d++) {
                    O[0][d] += p0 * v4[d];
                    O[1][d] += p1 * v4[d];
                    O[2][d] += p2 * v4[d];
                    O[3][d] += p3 * v4[d];
                }
            }
        }
    }

    #pragma unroll
    for (int i = 0; i < 4; i++) {
        float inv = 1.0f / l[i];
        int r = q0 + ty + 16 * i;
        half4 o;
        #pragma unroll
        for (int d = 0; d < 4; d++) o[d] = (_Float16)(O[i][d] * inv);
        *(half4*)&Y[base + (size_t)r * CC + tx * 4] = o;
    }
}

// ---------------- launch ----------------
extern "C" void kernel_launch(void* const* d_in, const int* in_sizes, int n_in,
                              void* d_out, int out_size, void* d_ws, size_t ws_size,
                              hipStream_t stream)
{
    const float* x      = (const float*)d_in[0];
    const float* ln1_g  = (const float*)d_in[1];
    const float* ln1_b  = (const float*)d_in[2];
    const float* wq     = (const float*)d_in[3];
    const float* bq     = (const float*)d_in[4];
    const float* wk     = (const float*)d_in[5];
    const float* bk     = (const float*)d_in[6];
    const float* wv     = (const float*)d_in[7];
    const float* bv     = (const float*)d_in[8];
    const float* wp     = (const float*)d_in[9];
    const float* bp     = (const float*)d_in[10];
    const float* ln2_g  = (const float*)d_in[11];
    const float* ln2_b  = (const float*)d_in[12];
    const float* w1     = (const float*)d_in[13];
    const float* b1     = (const float*)d_in[14];
    const float* w2     = (const float*)d_in[15];
    const float* b2     = (const float*)d_in[16];
    const float* gate_h = (const float*)d_in[17];
    const float* gate_f = (const float*)d_in[18];

    char* ws = (char*)d_ws;
    _Float16* WQh = (_Float16*)(ws + 0);
    _Float16* WKh = (_Float16*)(ws + 1179648);
    _Float16* WVh = (_Float16*)(ws + 2359296);
    _Float16* WPh = (_Float16*)(ws + 3538944);
    _Float16* W1h = (_Float16*)(ws + 4718592);
    _Float16* W2h = (_Float16*)(ws + 9437184);
    _Float16* XN  = (_Float16*)(ws + 14155776);
    _Float16* Qb  = (_Float16*)(ws + 39321600);
    _Float16* Kb  = (_Float16*)(ws + 64487424);
    _Float16* Vb  = (_Float16*)(ws + 89653248);
    _Float16* Yb  = (_Float16*)(ws + 114819072);
    float*    X1  = (float*)   (ws + 139984896);
    _Float16* XN2 = (_Float16*)(ws + 190316544);
    _Float16* F1  = (_Float16*)(ws + 14155776);  // aliases XN/Q/K/V (dead by then)

    // weight converts
    cvt_kernel<<<576, 256, 0, stream>>>(wq, WQh, 147456);
    cvt_kernel<<<576, 256, 0, stream>>>(wk, WKh, 147456);
    cvt_kernel<<<576, 256, 0, stream>>>(wv, WVh, 147456);
    cvt_kernel<<<576, 256, 0, stream>>>(wp, WPh, 147456);
    cvt_kernel<<<2304, 256, 0, stream>>>(w1, W1h, 589824);
    cvt_kernel<<<2304, 256, 0, stream>>>(w2, W2h, 589824);

    // LN1
    ln_kernel<<<ROWS, 256, 0, stream>>>(x, ln1_g, ln1_b, XN);

    // QKV projections
    dim3 g768(6, 128);
    gemm_kernel<0><<<g768, 256, 0, stream>>>(XN, WQh, bq, nullptr, nullptr, Qb, ROWS, CC, CC);
    gemm_kernel<0><<<g768, 256, 0, stream>>>(XN, WKh, bk, nullptr, nullptr, Kb, ROWS, CC, CC);
    gemm_kernel<0><<<g768, 256, 0, stream>>>(XN, WVh, bv, nullptr, nullptr, Vb, ROWS, CC, CC);

    // attention (head-masked)
    attn_kernel<<<dim3(16, HH, BB), 256, 0, stream>>>(Qb, Kb, Vb, gate_h, Yb);

    // proj + residual -> X1 (fp32)
    gemm_kernel<2><<<g768, 256, 0, stream>>>(Yb, WPh, bp, x, nullptr, X1, ROWS, CC, CC);

    // LN2
    ln_kernel<<<ROWS, 256, 0, stream>>>(X1, ln2_g, ln2_b, XN2);

    // MLP1: gelu-gated -> F1 fp16
    gemm_kernel<1><<<dim3(24, 128), 256, 0, stream>>>(XN2, W1h, b1, nullptr, gate_f, F1, ROWS, HIDN, CC);

    // MLP2 + residual -> out fp32
    gemm_kernel<2><<<g768, 256, 0, stream>>>(F1, W2h, b2, X1, nullptr, (float*)d_out, ROWS, CC, HIDN);
}

// Round 2
// 687.405 us; speedup vs baseline: 1.5230x; 1.5230x over previous
//
#include <hip/hip_runtime.h>

#define BB 16
#define NNN 1024
#define CC 768
#define HH 12
#define DD 64
#define HIDN 3072
#define ROWS (BB*NNN)   // 16384

typedef _Float16 half8 __attribute__((ext_vector_type(8)));
typedef _Float16 half4 __attribute__((ext_vector_type(4)));
typedef float floatx4 __attribute__((ext_vector_type(4)));

// ---------------- weight fp32 -> fp16 convert ----------------
__global__ void cvt_kernel(const float* __restrict__ src, _Float16* __restrict__ dst, int n4) {
    int i = blockIdx.x * blockDim.x + threadIdx.x;
    if (i < n4) {
        floatx4 v = ((const floatx4*)src)[i];
        half4 h;
        h[0] = (_Float16)v[0]; h[1] = (_Float16)v[1];
        h[2] = (_Float16)v[2]; h[3] = (_Float16)v[3];
        ((half4*)dst)[i] = h;
    }
}

// ---------------- LayerNorm (row of 768), fp32 in -> fp16 out ----------------
__global__ __launch_bounds__(256) void ln_kernel(const float* __restrict__ x,
                                                 const float* __restrict__ g,
                                                 const float* __restrict__ b,
                                                 _Float16* __restrict__ out) {
    int row = blockIdx.x;
    int t = threadIdx.x;
    const float* xr = x + (size_t)row * CC;
    float v0 = xr[t], v1 = xr[t + 256], v2 = xr[t + 512];
    float s = v0 + v1 + v2;
    float q = v0 * v0 + v1 * v1 + v2 * v2;
    #pragma unroll
    for (int m = 1; m < 64; m <<= 1) {
        s += __shfl_xor(s, m, 64);
        q += __shfl_xor(q, m, 64);
    }
    __shared__ float red[8];
    int wv = t >> 6, lane = t & 63;
    if (lane == 0) { red[wv] = s; red[wv + 4] = q; }
    __syncthreads();
    s = red[0] + red[1] + red[2] + red[3];
    q = red[4] + red[5] + red[6] + red[7];
    float mean = s * (1.0f / CC);
    float var = q * (1.0f / CC) - mean * mean;
    float rs = rsqrtf(var + 1e-5f);
    _Float16* orow = out + (size_t)row * CC;
    orow[t]       = (_Float16)((v0 - mean) * rs * g[t]       + b[t]);
    orow[t + 256] = (_Float16)((v1 - mean) * rs * g[t + 256] + b[t + 256]);
    orow[t + 512] = (_Float16)((v2 - mean) * rs * g[t + 512] + b[t + 512]);
}

// ---------------- MFMA GEMM: C[M,N] = A[M,K] @ W[N,K]^T + bias ----------------
// MODE 0: out fp16 = acc + bias                      (Q/K proj; hgate: skip masked head pairs)
// MODE 1: out fp16 = fmask * gelu(acc + bias)        (MLP1; gate = gate_f per out col)
// MODE 2: out fp32 = res + acc + bias                (proj / MLP2; hgate: skip zero K-blocks)
// MODE 3: out fp16 = acc + bias, written transposed per head: Vt[(b*H+h)*64+d][n]
template <int MODE>
__global__ __launch_bounds__(256) void gemm_kernel(
    const _Float16* __restrict__ A,
    const _Float16* __restrict__ W,
    const float* __restrict__ bias,
    const float* __restrict__ res,
    const float* __restrict__ gate,
    const float* __restrict__ hgate,
    void* __restrict__ outp,
    int M, int N, int K)
{
    int m0 = blockIdx.y * 128, n0 = blockIdx.x * 128;
    if ((MODE == 0 || MODE == 3) && hgate) {
        int h0 = n0 >> 6;   // 128 cols = 2 heads
        if (hgate[h0] <= 0.0f && hgate[h0 + 1] <= 0.0f) return;  // outputs never read
    }
    __shared__ _Float16 As[128][40];  // 40 = 32 + 8 pad (80B row stride, 16B aligned)
    __shared__ _Float16 Bs[128][40];
    int t = threadIdx.x;
    int lane = t & 63, wv = t >> 6;
    int wm = (wv >> 1) * 64, wn = (wv & 1) * 64;
    int lrow = lane & 15, quad = lane >> 4;

    floatx4 acc[4][4];
    #pragma unroll
    for (int i = 0; i < 4; i++)
        #pragma unroll
        for (int j = 0; j < 4; j++)
            acc[i][j] = (floatx4){0.f, 0.f, 0.f, 0.f};

    int srow = t >> 1;           // 0..127
    int scol = (t & 1) * 16;     // 0 or 16
    const _Float16* ag = A + (size_t)(m0 + srow) * K + scol;
    const _Float16* bg = W + (size_t)(n0 + srow) * K + scol;

    for (int k0 = 0; k0 < K; k0 += 32) {
        if (MODE == 2 && hgate && hgate[k0 >> 6] <= 0.0f) continue;  // A cols exactly zero
        half8 a0 = *(const half8*)(ag + k0);
        half8 a1 = *(const half8*)(ag + k0 + 8);
        half8 b0 = *(const half8*)(bg + k0);
        half8 b1 = *(const half8*)(bg + k0 + 8);
        __syncthreads();
        *(half8*)&As[srow][scol]     = a0;
        *(half8*)&As[srow][scol + 8] = a1;
        *(half8*)&Bs[srow][scol]     = b0;
        *(half8*)&Bs[srow][scol + 8] = b1;
        __syncthreads();
        half8 af[4], bf[4];
        #pragma unroll
        for (int i = 0; i < 4; i++) af[i] = *(const half8*)&As[wm + i * 16 + lrow][quad * 8];
        #pragma unroll
        for (int j = 0; j < 4; j++) bf[j] = *(const half8*)&Bs[wn + j * 16 + lrow][quad * 8];
        #pragma unroll
        for (int i = 0; i < 4; i++)
            #pragma unroll
            for (int j = 0; j < 4; j++)
                acc[i][j] = __builtin_amdgcn_mfma_f32_16x16x32_f16(af[i], bf[j], acc[i][j], 0, 0, 0);
    }

    // epilogue: C row = quad*4 + r (M side), col = lrow (N side)  [verified m89/m91 layout]
    #pragma unroll
    for (int i = 0; i < 4; i++) {
        #pragma unroll
        for (int j = 0; j < 4; j++) {
            int gn = n0 + wn + j * 16 + lrow;
            float bs = bias[gn];
            if (MODE == 3) {
                int gm0 = m0 + wm + i * 16 + quad * 4;
                int b_ = gm0 >> 10, n_ = gm0 & 1023;
                half4 pk;
                #pragma unroll
                for (int r = 0; r < 4; r++) pk[r] = (_Float16)(acc[i][j][r] + bs);
                size_t idx = ((size_t)(b_ * HH + (gn >> 6)) * 64 + (gn & 63)) * NNN + n_;
                *(half4*)&((_Float16*)outp)[idx] = pk;
            } else {
                #pragma unroll
                for (int r = 0; r < 4; r++) {
                    int gm = m0 + wm + i * 16 + quad * 4 + r;
                    float v = acc[i][j][r] + bs;
                    size_t idx = (size_t)gm * N + gn;
                    if (MODE == 0) {
                        ((_Float16*)outp)[idx] = (_Float16)v;
                    } else if (MODE == 1) {
                        float vv = (gate[gn] > 0.0f) ? 0.5f * v * (1.0f + erff(v * 0.70710678118f)) : 0.0f;
                        ((_Float16*)outp)[idx] = (_Float16)vv;
                    } else {
                        ((float*)outp)[idx] = res[idx] + v;
                    }
                }
            }
        }
    }
}

// ---------------- MFMA flash attention ----------------
// Block: 256 thr = 4 waves; one block per (b, h, 64-row q tile); 16 k-tiles of 64 keys.
// Wave w owns q rows [16w,16w+16). S/PV via mfma_f32_16x16x32_f16.
// Frag layouts (verified m89/m91): A[m=lane&15][k=quad*8+j], B[n=lane&15][k=quad*8+j],
// C row=quad*4+r col=lane&15.
__global__ __launch_bounds__(256) void attn_kernel(
    const _Float16* __restrict__ Q,    // [b][n][h*64+d]
    const _Float16* __restrict__ Kp,   // [b][n][h*64+d]
    const _Float16* __restrict__ Vt,   // [(b*H+h)*64+d][n]  (pre-transposed by MODE 3 GEMM)
    const float* __restrict__ gate_h,
    _Float16* __restrict__ Y)          // [b][n][h*64+d]
{
    int qt = blockIdx.x;   // 0..15
    int h  = blockIdx.y;   // 0..11
    int b  = blockIdx.z;   // 0..15
    int t = threadIdx.x;
    int q0 = qt * 64;
    size_t ybase = ((size_t)b * NNN + q0) * CC + h * DD;

    if (gate_h[h] <= 0.0f) {   // masked head: y*hm == 0 exactly
        int r = t >> 2, c = (t & 3) * 16;
        half8 z = {(_Float16)0, (_Float16)0, (_Float16)0, (_Float16)0,
                   (_Float16)0, (_Float16)0, (_Float16)0, (_Float16)0};
        *(half8*)&Y[ybase + (size_t)r * CC + c]     = z;
        *(half8*)&Y[ybase + (size_t)r * CC + c + 8] = z;
        return;
    }

    __shared__ _Float16 Qs[64][72];   // stride 72 fp16 = 144B: balanced banks for b128
    __shared__ _Float16 Ks[64][72];
    __shared__ _Float16 Vs[64][72];   // Vs[d][key]
    __shared__ _Float16 Ps[64][72];   // P round-trip + final O transpose

    int lane = t & 63, w = t >> 6;
    int L = lane & 15, quad = lane >> 4;

    {   // stage Q tile, pre-scaled by D^-0.5 = 0.125 (exact in fp16)
        int r = t >> 2, c = (t & 3) * 16;
        const half8* src = (const half8*)(Q + ((size_t)b * NNN + q0 + r) * CC + h * DD + c);
        half8 h0 = src[0], h1 = src[1];
        #pragma unroll
        for (int e = 0; e < 8; e++) { h0[e] = h0[e] * (_Float16)0.125f; h1[e] = h1[e] * (_Float16)0.125f; }
        *(half8*)&Qs[r][c]     = h0;
        *(half8*)&Qs[r][c + 8] = h1;
    }

    floatx4 O[4];           // O[t4]: rows quad*4+r, cols d = 16*t4 + L
    float m_[4], l_[4];
    #pragma unroll
    for (int i = 0; i < 4; i++) { O[i] = (floatx4){0.f,0.f,0.f,0.f}; m_[i] = -1e30f; l_[i] = 0.0f; }

    const size_t kbase = (size_t)b * NNN * CC + h * DD;
    const size_t vbase = (size_t)(b * HH + h) * DD * NNN;

    for (int kt = 0; kt < 16; ++kt) {
        int k0 = kt * 64;
        __syncthreads();   // prior iteration's frag reads done before restage
        {
            int r = t >> 2, c = (t & 3) * 16;
            const half8* ks = (const half8*)(Kp + kbase + (size_t)(k0 + r) * CC + c);
            half8 ka = ks[0], kb = ks[1];
            *(half8*)&Ks[r][c]     = ka;
            *(half8*)&Ks[r][c + 8] = kb;
            const half8* vs = (const half8*)(Vt + vbase + (size_t)r * NNN + k0 + c);
            half8 va = vs[0], vb = vs[1];
            *(half8*)&Vs[r][c]     = va;
            *(half8*)&Vs[r][c + 8] = vb;
        }
        __syncthreads();

        // S = Q K^T : per wave 16q x 64key, 8 MFMAs
        half8 aq0 = *(const half8*)&Qs[16 * w + L][quad * 8];
        half8 aq1 = *(const half8*)&Qs[16 * w + L][quad * 8 + 32];
        floatx4 s[4];
        #pragma unroll
        for (int j = 0; j < 4; j++) {
            half8 b0 = *(const half8*)&Ks[16 * j + L][quad * 8];
            half8 b1 = *(const half8*)&Ks[16 * j + L][quad * 8 + 32];
            floatx4 z = (floatx4){0.f,0.f,0.f,0.f};
            z = __builtin_amdgcn_mfma_f32_16x16x32_f16(aq0, b0, z, 0, 0, 0);
            z = __builtin_amdgcn_mfma_f32_16x16x32_f16(aq1, b1, z, 0, 0, 0);
            s[j] = z;
        }

        // online softmax in C layout: lane holds rows q=quad*4+r, cols key=16j+L
        #pragma unroll
        for (int r = 0; r < 4; r++) {
            float mx = fmaxf(fmaxf(s[0][r], s[1][r]), fmaxf(s[2][r], s[3][r]));
            mx = fmaxf(mx, __shfl_xor(mx, 1, 64));
            mx = fmaxf(mx, __shfl_xor(mx, 2, 64));
            mx = fmaxf(mx, __shfl_xor(mx, 4, 64));
            mx = fmaxf(mx, __shfl_xor(mx, 8, 64));
            float mnew = fmaxf(m_[r], mx);
            float alpha = __expf(m_[r] - mnew);
            m_[r] = mnew;
            float ps = 0.0f;
            #pragma unroll
            for (int j = 0; j < 4; j++) {
                float p = __expf(s[j][r] - mnew);
                s[j][r] = p; ps += p;
                Ps[16 * w + quad * 4 + r][L + 16 * j] = (_Float16)p;
            }
            ps += __shfl_xor(ps, 1, 64);
            ps += __shfl_xor(ps, 2, 64);
            ps += __shfl_xor(ps, 4, 64);
            ps += __shfl_xor(ps, 8, 64);
            l_[r] = l_[r] * alpha + ps;
            #pragma unroll
            for (int t4 = 0; t4 < 4; t4++) O[t4][r] *= alpha;
        }
        __syncthreads();   // Ps visible (same-wave in practice; barrier is cheap insurance)

        // O += P @ V : A = Ps rows 16w.., B = Vs[d][key], 8 MFMAs
        half8 ap0 = *(const half8*)&Ps[16 * w + L][quad * 8];
        half8 ap1 = *(const half8*)&Ps[16 * w + L][quad * 8 + 32];
        #pragma unroll
        for (int t4 = 0; t4 < 4; t4++) {
            half8 b0 = *(const half8*)&Vs[16 * t4 + L][quad * 8];
            half8 b1 = *(const half8*)&Vs[16 * t4 + L][quad * 8 + 32];
            O[t4] = __builtin_amdgcn_mfma_f32_16x16x32_f16(ap0, b0, O[t4], 0, 0, 0);
            O[t4] = __builtin_amdgcn_mfma_f32_16x16x32_f16(ap1, b1, O[t4], 0, 0, 0);
        }
    }

    // epilogue: normalize, transpose through Ps, coalesced fp16 store
    __syncthreads();
    #pragma unroll
    for (int r = 0; r < 4; r++) {
        float inv = 1.0f / l_[r];
        #pragma unroll
        for (int t4 = 0; t4 < 4; t4++)
            Ps[16 * w + quad * 4 + r][16 * t4 + L] = (_Float16)(O[t4][r] * inv);
    }
    __syncthreads();
    {
        int r = t >> 2, c = (t & 3) * 16;   // row t>>2 belongs to this thread's own wave
        half8 o0 = *(const half8*)&Ps[r][c];
        half8 o1 = *(const half8*)&Ps[r][c + 8];
        *(half8*)&Y[ybase + (size_t)r * CC + c]     = o0;
        *(half8*)&Y[ybase + (size_t)r * CC + c + 8] = o1;
    }
}

// ---------------- launch ----------------
extern "C" void kernel_launch(void* const* d_in, const int* in_sizes, int n_in,
                              void* d_out, int out_size, void* d_ws, size_t ws_size,
                              hipStream_t stream)
{
    const float* x      = (const float*)d_in[0];
    const float* ln1_g  = (const float*)d_in[1];
    const float* ln1_b  = (const float*)d_in[2];
    const float* wq     = (const float*)d_in[3];
    const float* bq     = (const float*)d_in[4];
    const float* wk     = (const float*)d_in[5];
    const float* bk     = (const float*)d_in[6];
    const float* wv     = (const float*)d_in[7];
    const float* bv     = (const float*)d_in[8];
    const float* wp     = (const float*)d_in[9];
    const float* bp     = (const float*)d_in[10];
    const float* ln2_g  = (const float*)d_in[11];
    const float* ln2_b  = (const float*)d_in[12];
    const float* w1     = (const float*)d_in[13];
    const float* b1     = (const float*)d_in[14];
    const float* w2     = (const float*)d_in[15];
    const float* b2     = (const float*)d_in[16];
    const float* gate_h = (const float*)d_in[17];
    const float* gate_f = (const float*)d_in[18];

    char* ws = (char*)d_ws;
    _Float16* WQh = (_Float16*)(ws + 0);
    _Float16* WKh = (_Float16*)(ws + 1179648);
    _Float16* WVh = (_Float16*)(ws + 2359296);
    _Float16* WPh = (_Float16*)(ws + 3538944);
    _Float16* W1h = (_Float16*)(ws + 4718592);
    _Float16* W2h = (_Float16*)(ws + 9437184);
    _Float16* XN  = (_Float16*)(ws + 14155776);
    _Float16* Qb  = (_Float16*)(ws + 39321600);
    _Float16* Kb  = (_Float16*)(ws + 64487424);
    _Float16* Vtb = (_Float16*)(ws + 89653248);   // V transposed: [(b*H+h)*64+d][n]
    _Float16* Yb  = (_Float16*)(ws + 114819072);
    float*    X1  = (float*)   (ws + 139984896);
    _Float16* XN2 = (_Float16*)(ws + 190316544);
    _Float16* F1  = (_Float16*)(ws + 14155776);  // aliases XN/Q/K (dead by then)

    // weight converts
    cvt_kernel<<<576, 256, 0, stream>>>(wq, WQh, 147456);
    cvt_kernel<<<576, 256, 0, stream>>>(wk, WKh, 147456);
    cvt_kernel<<<576, 256, 0, stream>>>(wv, WVh, 147456);
    cvt_kernel<<<576, 256, 0, stream>>>(wp, WPh, 147456);
    cvt_kernel<<<2304, 256, 0, stream>>>(w1, W1h, 589824);
    cvt_kernel<<<2304, 256, 0, stream>>>(w2, W2h, 589824);

    // LN1
    ln_kernel<<<ROWS, 256, 0, stream>>>(x, ln1_g, ln1_b, XN);

    // QKV projections (masked head-pairs skipped; their outputs are never read)
    dim3 g768(6, 128);
    gemm_kernel<0><<<g768, 256, 0, stream>>>(XN, WQh, bq, nullptr, nullptr, gate_h, Qb, ROWS, CC, CC);
    gemm_kernel<0><<<g768, 256, 0, stream>>>(XN, WKh, bk, nullptr, nullptr, gate_h, Kb, ROWS, CC, CC);
    gemm_kernel<3><<<g768, 256, 0, stream>>>(XN, WVh, bv, nullptr, nullptr, gate_h, Vtb, ROWS, CC, CC);

    // attention (MFMA, head-masked)
    attn_kernel<<<dim3(16, HH, BB), 256, 0, stream>>>(Qb, Kb, Vtb, gate_h, Yb);

    // proj + residual -> X1 (fp32); K-blocks of masked heads are exactly zero -> skipped
    gemm_kernel<2><<<g768, 256, 0, stream>>>(Yb, WPh, bp, x, nullptr, gate_h, X1, ROWS, CC, CC);

    // LN2
    ln_kernel<<<ROWS, 256, 0, stream>>>(X1, ln2_g, ln2_b, XN2);

    // MLP1: gelu-gated -> F1 fp16
    gemm_kernel<1><<<dim3(24, 128), 256, 0, stream>>>(XN2, W1h, b1, nullptr, gate_f, nullptr, F1, ROWS, HIDN, CC);

    // MLP2 + residual -> out fp32
    gemm_kernel<2><<<g768, 256, 0, stream>>>(F1, W2h, b2, X1, nullptr, nullptr, (float*)d_out, ROWS, CC, HIDN);
}

// Round 3
// 683.165 us; speedup vs baseline: 1.5325x; 1.0062x over previous
//
#include <hip/hip_runtime.h>

#define BB 16
#define NNN 1024
#define CC 768
#define HH 12
#define DD 64
#define HIDN 3072
#define ROWS (BB*NNN)   // 16384

typedef _Float16 half8 __attribute__((ext_vector_type(8)));
typedef _Float16 half4 __attribute__((ext_vector_type(4)));
typedef float floatx4 __attribute__((ext_vector_type(4)));

#define GLOAD_LDS(g, l) __builtin_amdgcn_global_load_lds( \
    (const __attribute__((address_space(1))) void*)(g),    \
    (__attribute__((address_space(3))) void*)(l), 16, 0, 0)

// ---------------- weight fp32 -> fp16 convert ----------------
__global__ void cvt_kernel(const float* __restrict__ src, _Float16* __restrict__ dst, int n4) {
    int i = blockIdx.x * blockDim.x + threadIdx.x;
    if (i < n4) {
        floatx4 v = ((const floatx4*)src)[i];
        half4 h;
        h[0] = (_Float16)v[0]; h[1] = (_Float16)v[1];
        h[2] = (_Float16)v[2]; h[3] = (_Float16)v[3];
        ((half4*)dst)[i] = h;
    }
}

// ---------------- LayerNorm (row of 768), fp32 in -> fp16 out ----------------
__global__ __launch_bounds__(256) void ln_kernel(const float* __restrict__ x,
                                                 const float* __restrict__ g,
                                                 const float* __restrict__ b,
                                                 _Float16* __restrict__ out) {
    int row = blockIdx.x;
    int t = threadIdx.x;
    const float* xr = x + (size_t)row * CC;
    float v0 = xr[t], v1 = xr[t + 256], v2 = xr[t + 512];
    float s = v0 + v1 + v2;
    float q = v0 * v0 + v1 * v1 + v2 * v2;
    #pragma unroll
    for (int m = 1; m < 64; m <<= 1) {
        s += __shfl_xor(s, m, 64);
        q += __shfl_xor(q, m, 64);
    }
    __shared__ float red[8];
    int wv = t >> 6, lane = t & 63;
    if (lane == 0) { red[wv] = s; red[wv + 4] = q; }
    __syncthreads();
    s = red[0] + red[1] + red[2] + red[3];
    q = red[4] + red[5] + red[6] + red[7];
    float mean = s * (1.0f / CC);
    float var = q * (1.0f / CC) - mean * mean;
    float rs = rsqrtf(var + 1e-5f);
    _Float16* orow = out + (size_t)row * CC;
    orow[t]       = (_Float16)((v0 - mean) * rs * g[t]       + b[t]);
    orow[t + 256] = (_Float16)((v1 - mean) * rs * g[t + 256] + b[t + 256]);
    orow[t + 512] = (_Float16)((v2 - mean) * rs * g[t + 512] + b[t + 512]);
}

// ---------------- MFMA GEMM (m97 structure): C[M,N] = A[M,K] @ W[N,K]^T + bias ----
// Staging: global_load_lds dwordx4, LDS dest = wave_base + lane*16 (no pad possible),
// bank swizzle moved to the GLOBAL side: chunk kc of row r stored at kc ^ ((r>>2)&3).
// Fragment read chunk = quad ^ ((L>>2)&3) -> each 16-lane b128 phase covers all 8
// start banks twice = conflict-free minimum.
// MODE 0: out fp16 = acc + bias                      (Q/K proj; hgate: skip masked head pairs)
// MODE 1: out fp16 = fmask * gelu(acc + bias)        (MLP1; gate = gate_f per out col)
// MODE 2: out fp32 = res + acc + bias                (proj / MLP2; hgate: skip zero K-blocks)
// MODE 3: out fp16 = acc + bias, written transposed per head: Vt[(b*H+h)*64+d][n]
template <int MODE>
__global__ __launch_bounds__(256) void gemm_kernel(
    const _Float16* __restrict__ A,
    const _Float16* __restrict__ W,
    const float* __restrict__ bias,
    const float* __restrict__ res,
    const float* __restrict__ gate,
    const float* __restrict__ hgate,
    void* __restrict__ outp,
    int M, int N, int K)
{
    int m0 = blockIdx.y * 128, n0 = blockIdx.x * 128;
    if ((MODE == 0 || MODE == 3) && hgate) {
        int h0 = n0 >> 6;   // 128 cols = 2 heads
        if (hgate[h0] <= 0.0f && hgate[h0 + 1] <= 0.0f) return;  // outputs never read
    }
    __shared__ _Float16 As[128 * 32];   // row stride 32 halfs (64B), no pad (global_load_lds)
    __shared__ _Float16 Bs[128 * 32];
    int t = threadIdx.x;
    int lane = t & 63, w = t >> 6;
    int wm = (w >> 1) * 64, wn = (w & 1) * 64;
    int L = lane & 15, quad = lane >> 4;
    int rchunk = (quad ^ ((L >> 2) & 3)) * 8;   // swizzled k-chunk for fragment reads

    floatx4 acc[4][4];
    #pragma unroll
    for (int i = 0; i < 4; i++)
        #pragma unroll
        for (int j = 0; j < 4; j++)
            acc[i][j] = (floatx4){0.f, 0.f, 0.f, 0.f};

    // staging source pointers: physical chunk pc = issue*256 + t; row = pc>>2,
    // logical kc = (pc&3) ^ ((pc>>4)&3)  [= (row>>2)&3 swizzle]
    const _Float16* agp[2];
    const _Float16* bgp[2];
    #pragma unroll
    for (int i = 0; i < 2; i++) {
        int pc = i * 256 + t;
        int row = pc >> 2;
        int kc = (pc & 3) ^ ((pc >> 4) & 3);
        agp[i] = A + (size_t)(m0 + row) * K + kc * 8;
        bgp[i] = W + (size_t)(n0 + row) * K + kc * 8;
    }
    unsigned wb = (unsigned)w * 512;   // wave-uniform LDS base (halfs) per issue block

    for (int k0 = 0; k0 < K; k0 += 32) {
        if (MODE == 2 && hgate && hgate[k0 >> 6] <= 0.0f) continue;  // A cols exactly zero
        __syncthreads();   // prior iteration's fragment reads done before overwrite
        #pragma unroll
        for (int i = 0; i < 2; i++) {
            GLOAD_LDS(agp[i] + k0, As + i * 2048 + wb);
            GLOAD_LDS(bgp[i] + k0, Bs + i * 2048 + wb);
        }
        __syncthreads();   // drains vmcnt(0): LDS tiles complete
        half8 af[4], bf[4];
        #pragma unroll
        for (int i = 0; i < 4; i++) af[i] = *(const half8*)&As[(wm + i * 16 + L) * 32 + rchunk];
        #pragma unroll
        for (int j = 0; j < 4; j++) bf[j] = *(const half8*)&Bs[(wn + j * 16 + L) * 32 + rchunk];
        #pragma unroll
        for (int i = 0; i < 4; i++)
            #pragma unroll
            for (int j = 0; j < 4; j++)
                acc[i][j] = __builtin_amdgcn_mfma_f32_16x16x32_f16(af[i], bf[j], acc[i][j], 0, 0, 0);
    }

    // epilogue: C row = quad*4 + r (M side), col = lrow (N side)  [verified m89/m91 layout]
    #pragma unroll
    for (int i = 0; i < 4; i++) {
        #pragma unroll
        for (int j = 0; j < 4; j++) {
            int gn = n0 + wn + j * 16 + L;
            float bs = bias[gn];
            if (MODE == 3) {
                int gm0 = m0 + wm + i * 16 + quad * 4;
                int b_ = gm0 >> 10, n_ = gm0 & 1023;
                half4 pk;
                #pragma unroll
                for (int r = 0; r < 4; r++) pk[r] = (_Float16)(acc[i][j][r] + bs);
                size_t idx = ((size_t)(b_ * HH + (gn >> 6)) * 64 + (gn & 63)) * NNN + n_;
                *(half4*)&((_Float16*)outp)[idx] = pk;
            } else {
                #pragma unroll
                for (int r = 0; r < 4; r++) {
                    int gm = m0 + wm + i * 16 + quad * 4 + r;
                    float v = acc[i][j][r] + bs;
                    size_t idx = (size_t)gm * N + gn;
                    if (MODE == 0) {
                        ((_Float16*)outp)[idx] = (_Float16)v;
                    } else if (MODE == 1) {
                        float vv = (gate[gn] > 0.0f) ? 0.5f * v * (1.0f + erff(v * 0.70710678118f)) : 0.0f;
                        ((_Float16*)outp)[idx] = (_Float16)vv;
                    } else {
                        ((float*)outp)[idx] = res[idx] + v;
                    }
                }
            }
        }
    }
}

// ---------------- MFMA flash attention ----------------
// Block: 256 thr = 4 waves; one block per (b, h, 64-row q tile); 16 k-tiles of 64 keys.
// Wave w owns q rows [16w,16w+16). S/PV via mfma_f32_16x16x32_f16.
__global__ __launch_bounds__(256) void attn_kernel(
    const _Float16* __restrict__ Q,    // [b][n][h*64+d]
    const _Float16* __restrict__ Kp,   // [b][n][h*64+d]
    const _Float16* __restrict__ Vt,   // [(b*H+h)*64+d][n]  (pre-transposed by MODE 3 GEMM)
    const float* __restrict__ gate_h,
    _Float16* __restrict__ Y)          // [b][n][h*64+d]
{
    int qt = blockIdx.x;   // 0..15
    int h  = blockIdx.y;   // 0..11
    int b  = blockIdx.z;   // 0..15
    int t = threadIdx.x;
    int q0 = qt * 64;
    size_t ybase = ((size_t)b * NNN + q0) * CC + h * DD;

    if (gate_h[h] <= 0.0f) {   // masked head: y*hm == 0 exactly
        int r = t >> 2, c = (t & 3) * 16;
        half8 z = {(_Float16)0, (_Float16)0, (_Float16)0, (_Float16)0,
                   (_Float16)0, (_Float16)0, (_Float16)0, (_Float16)0};
        *(half8*)&Y[ybase + (size_t)r * CC + c]     = z;
        *(half8*)&Y[ybase + (size_t)r * CC + c + 8] = z;
        return;
    }

    __shared__ _Float16 Qs[64][72];
    __shared__ _Float16 Ks[64][72];
    __shared__ _Float16 Vs[64][72];   // Vs[d][key]
    __shared__ _Float16 Ps[64][72];   // P round-trip + final O transpose

    int lane = t & 63, w = t >> 6;
    int L = lane & 15, quad = lane >> 4;

    {   // stage Q tile, pre-scaled by D^-0.5 = 0.125 (exact in fp16)
        int r = t >> 2, c = (t & 3) * 16;
        const half8* src = (const half8*)(Q + ((size_t)b * NNN + q0 + r) * CC + h * DD + c);
        half8 h0 = src[0], h1 = src[1];
        #pragma unroll
        for (int e = 0; e < 8; e++) { h0[e] = h0[e] * (_Float16)0.125f; h1[e] = h1[e] * (_Float16)0.125f; }
        *(half8*)&Qs[r][c]     = h0;
        *(half8*)&Qs[r][c + 8] = h1;
    }

    floatx4 O[4];           // O[t4]: rows quad*4+r, cols d = 16*t4 + L
    float m_[4], l_[4];
    #pragma unroll
    for (int i = 0; i < 4; i++) { O[i] = (floatx4){0.f,0.f,0.f,0.f}; m_[i] = -1e30f; l_[i] = 0.0f; }

    const size_t kbase = (size_t)b * NNN * CC + h * DD;
    const size_t vbase = (size_t)(b * HH + h) * DD * NNN;

    for (int kt = 0; kt < 16; ++kt) {
        int k0 = kt * 64;
        __syncthreads();
        {
            int r = t >> 2, c = (t & 3) * 16;
            const half8* ks = (const half8*)(Kp + kbase + (size_t)(k0 + r) * CC + c);
            half8 ka = ks[0], kb = ks[1];
            *(half8*)&Ks[r][c]     = ka;
            *(half8*)&Ks[r][c + 8] = kb;
            const half8* vs = (const half8*)(Vt + vbase + (size_t)r * NNN + k0 + c);
            half8 va = vs[0], vb = vs[1];
            *(half8*)&Vs[r][c]     = va;
            *(half8*)&Vs[r][c + 8] = vb;
        }
        __syncthreads();

        // S = Q K^T : per wave 16q x 64key, 8 MFMAs
        half8 aq0 = *(const half8*)&Qs[16 * w + L][quad * 8];
        half8 aq1 = *(const half8*)&Qs[16 * w + L][quad * 8 + 32];
        floatx4 s[4];
        #pragma unroll
        for (int j = 0; j < 4; j++) {
            half8 b0 = *(const half8*)&Ks[16 * j + L][quad * 8];
            half8 b1 = *(const half8*)&Ks[16 * j + L][quad * 8 + 32];
            floatx4 z = (floatx4){0.f,0.f,0.f,0.f};
            z = __builtin_amdgcn_mfma_f32_16x16x32_f16(aq0, b0, z, 0, 0, 0);
            z = __builtin_amdgcn_mfma_f32_16x16x32_f16(aq1, b1, z, 0, 0, 0);
            s[j] = z;
        }

        // online softmax in C layout: lane holds rows q=quad*4+r, cols key=16j+L
        #pragma unroll
        for (int r = 0; r < 4; r++) {
            float mx = fmaxf(fmaxf(s[0][r], s[1][r]), fmaxf(s[2][r], s[3][r]));
            mx = fmaxf(mx, __shfl_xor(mx, 1, 64));
            mx = fmaxf(mx, __shfl_xor(mx, 2, 64));
            mx = fmaxf(mx, __shfl_xor(mx, 4, 64));
            mx = fmaxf(mx, __shfl_xor(mx, 8, 64));
            float mnew = fmaxf(m_[r], mx);
            float alpha = __expf(m_[r] - mnew);
            m_[r] = mnew;
            float ps = 0.0f;
            #pragma unroll
            for (int j = 0; j < 4; j++) {
                float p = __expf(s[j][r] - mnew);
                s[j][r] = p; ps += p;
                Ps[16 * w + quad * 4 + r][L + 16 * j] = (_Float16)p;
            }
            ps += __shfl_xor(ps, 1, 64);
            ps += __shfl_xor(ps, 2, 64);
            ps += __shfl_xor(ps, 4, 64);
            ps += __shfl_xor(ps, 8, 64);
            l_[r] = l_[r] * alpha + ps;
            #pragma unroll
            for (int t4 = 0; t4 < 4; t4++) O[t4][r] *= alpha;
        }
        __syncthreads();

        // O += P @ V : A = Ps rows 16w.., B = Vs[d][key], 8 MFMAs
        half8 ap0 = *(const half8*)&Ps[16 * w + L][quad * 8];
        half8 ap1 = *(const half8*)&Ps[16 * w + L][quad * 8 + 32];
        #pragma unroll
        for (int t4 = 0; t4 < 4; t4++) {
            half8 b0 = *(const half8*)&Vs[16 * t4 + L][quad * 8];
            half8 b1 = *(const half8*)&Vs[16 * t4 + L][quad * 8 + 32];
            O[t4] = __builtin_amdgcn_mfma_f32_16x16x32_f16(ap0, b0, O[t4], 0, 0, 0);
            O[t4] = __builtin_amdgcn_mfma_f32_16x16x32_f16(ap1, b1, O[t4], 0, 0, 0);
        }
    }

    // epilogue: normalize, transpose through Ps, coalesced fp16 store
    __syncthreads();
    #pragma unroll
    for (int r = 0; r < 4; r++) {
        float inv = 1.0f / l_[r];
        #pragma unroll
        for (int t4 = 0; t4 < 4; t4++)
            Ps[16 * w + quad * 4 + r][16 * t4 + L] = (_Float16)(O[t4][r] * inv);
    }
    __syncthreads();
    {
        int r = t >> 2, c = (t & 3) * 16;
        half8 o0 = *(const half8*)&Ps[r][c];
        half8 o1 = *(const half8*)&Ps[r][c + 8];
        *(half8*)&Y[ybase + (size_t)r * CC + c]     = o0;
        *(half8*)&Y[ybase + (size_t)r * CC + c + 8] = o1;
    }
}

// ---------------- launch ----------------
extern "C" void kernel_launch(void* const* d_in, const int* in_sizes, int n_in,
                              void* d_out, int out_size, void* d_ws, size_t ws_size,
                              hipStream_t stream)
{
    const float* x      = (const float*)d_in[0];
    const float* ln1_g  = (const float*)d_in[1];
    const float* ln1_b  = (const float*)d_in[2];
    const float* wq     = (const float*)d_in[3];
    const float* bq     = (const float*)d_in[4];
    const float* wk     = (const float*)d_in[5];
    const float* bk     = (const float*)d_in[6];
    const float* wv     = (const float*)d_in[7];
    const float* bv     = (const float*)d_in[8];
    const float* wp     = (const float*)d_in[9];
    const float* bp     = (const float*)d_in[10];
    const float* ln2_g  = (const float*)d_in[11];
    const float* ln2_b  = (const float*)d_in[12];
    const float* w1     = (const float*)d_in[13];
    const float* b1     = (const float*)d_in[14];
    const float* w2     = (const float*)d_in[15];
    const float* b2     = (const float*)d_in[16];
    const float* gate_h = (const float*)d_in[17];
    const float* gate_f = (const float*)d_in[18];

    char* ws = (char*)d_ws;
    _Float16* WQh = (_Float16*)(ws + 0);
    _Float16* WKh = (_Float16*)(ws + 1179648);
    _Float16* WVh = (_Float16*)(ws + 2359296);
    _Float16* WPh = (_Float16*)(ws + 3538944);
    _Float16* W1h = (_Float16*)(ws + 4718592);
    _Float16* W2h = (_Float16*)(ws + 9437184);
    _Float16* XN  = (_Float16*)(ws + 14155776);
    _Float16* Qb  = (_Float16*)(ws + 39321600);
    _Float16* Kb  = (_Float16*)(ws + 64487424);
    _Float16* Vtb = (_Float16*)(ws + 89653248);   // V transposed: [(b*H+h)*64+d][n]
    _Float16* Yb  = (_Float16*)(ws + 114819072);
    float*    X1  = (float*)   (ws + 139984896);
    _Float16* XN2 = (_Float16*)(ws + 190316544);
    _Float16* F1  = (_Float16*)(ws + 14155776);  // aliases XN/Q/K (dead by then)

    // weight converts
    cvt_kernel<<<576, 256, 0, stream>>>(wq, WQh, 147456);
    cvt_kernel<<<576, 256, 0, stream>>>(wk, WKh, 147456);
    cvt_kernel<<<576, 256, 0, stream>>>(wv, WVh, 147456);
    cvt_kernel<<<576, 256, 0, stream>>>(wp, WPh, 147456);
    cvt_kernel<<<2304, 256, 0, stream>>>(w1, W1h, 589824);
    cvt_kernel<<<2304, 256, 0, stream>>>(w2, W2h, 589824);

    // LN1
    ln_kernel<<<ROWS, 256, 0, stream>>>(x, ln1_g, ln1_b, XN);

    // QKV projections (masked head-pairs skipped; their outputs are never read)
    dim3 g768(6, 128);
    gemm_kernel<0><<<g768, 256, 0, stream>>>(XN, WQh, bq, nullptr, nullptr, gate_h, Qb, ROWS, CC, CC);
    gemm_kernel<0><<<g768, 256, 0, stream>>>(XN, WKh, bk, nullptr, nullptr, gate_h, Kb, ROWS, CC, CC);
    gemm_kernel<3><<<g768, 256, 0, stream>>>(XN, WVh, bv, nullptr, nullptr, gate_h, Vtb, ROWS, CC, CC);

    // attention (MFMA, head-masked)
    attn_kernel<<<dim3(16, HH, BB), 256, 0, stream>>>(Qb, Kb, Vtb, gate_h, Yb);

    // proj + residual -> X1 (fp32); K-blocks of masked heads are exactly zero -> skipped
    gemm_kernel<2><<<g768, 256, 0, stream>>>(Yb, WPh, bp, x, nullptr, gate_h, X1, ROWS, CC, CC);

    // LN2
    ln_kernel<<<ROWS, 256, 0, stream>>>(X1, ln2_g, ln2_b, XN2);

    // MLP1: gelu-gated -> F1 fp16
    gemm_kernel<1><<<dim3(24, 128), 256, 0, stream>>>(XN2, W1h, b1, nullptr, gate_f, nullptr, F1, ROWS, HIDN, CC);

    // MLP2 + residual -> out fp32
    gemm_kernel<2><<<g768, 256, 0, stream>>>(F1, W2h, b2, X1, nullptr, nullptr, (float*)d_out, ROWS, CC, HIDN);
}

// Round 4
// 655.298 us; speedup vs baseline: 1.5976x; 1.0425x over previous
//
#include <hip/hip_runtime.h>

#define BB 16
#define NNN 1024
#define CC 768
#define HH 12
#define DD 64
#define HIDN 3072
#define ROWS (BB*NNN)   // 16384

typedef _Float16 half8 __attribute__((ext_vector_type(8)));
typedef _Float16 half4 __attribute__((ext_vector_type(4)));
typedef float floatx4 __attribute__((ext_vector_type(4)));

#define GLOAD_LDS(g, l) __builtin_amdgcn_global_load_lds( \
    (const __attribute__((address_space(1))) void*)(g),    \
    (__attribute__((address_space(3))) void*)(l), 16, 0, 0)

// ---------------- weight fp32 -> fp16 convert ----------------
__global__ void cvt_kernel(const float* __restrict__ src, _Float16* __restrict__ dst, int n4) {
    int i = blockIdx.x * blockDim.x + threadIdx.x;
    if (i < n4) {
        floatx4 v = ((const floatx4*)src)[i];
        half4 h;
        h[0] = (_Float16)v[0]; h[1] = (_Float16)v[1];
        h[2] = (_Float16)v[2]; h[3] = (_Float16)v[3];
        ((half4*)dst)[i] = h;
    }
}

// ---------------- LayerNorm (row of 768), fp32 in -> fp16 out ----------------
__global__ __launch_bounds__(256) void ln_kernel(const float* __restrict__ x,
                                                 const float* __restrict__ g,
                                                 const float* __restrict__ b,
                                                 _Float16* __restrict__ out) {
    int row = blockIdx.x;
    int t = threadIdx.x;
    const float* xr = x + (size_t)row * CC;
    float v0 = xr[t], v1 = xr[t + 256], v2 = xr[t + 512];
    float s = v0 + v1 + v2;
    float q = v0 * v0 + v1 * v1 + v2 * v2;
    #pragma unroll
    for (int m = 1; m < 64; m <<= 1) {
        s += __shfl_xor(s, m, 64);
        q += __shfl_xor(q, m, 64);
    }
    __shared__ float red[8];
    int wv = t >> 6, lane = t & 63;
    if (lane == 0) { red[wv] = s; red[wv + 4] = q; }
    __syncthreads();
    s = red[0] + red[1] + red[2] + red[3];
    q = red[4] + red[5] + red[6] + red[7];
    float mean = s * (1.0f / CC);
    float var = q * (1.0f / CC) - mean * mean;
    float rs = rsqrtf(var + 1e-5f);
    _Float16* orow = out + (size_t)row * CC;
    orow[t]       = (_Float16)((v0 - mean) * rs * g[t]       + b[t]);
    orow[t + 256] = (_Float16)((v1 - mean) * rs * g[t + 256] + b[t + 256]);
    orow[t + 512] = (_Float16)((v2 - mean) * rs * g[t + 512] + b[t + 512]);
}

// ---------------- MFMA GEMM (m97 staging), tile TM x 128 ----------------
// MODE 0: merged QKV. N=2304; segment s = n0/768 routes epilogue:
//         s=0 -> Q fp16 [m][col], s=1 -> K fp16 [m][col],
//         s=2 -> V transposed per head: Vt[(b*H+h)*64+d][n].  hgate skips masked head pairs.
// MODE 1: out fp16 = fmask * gelu(acc + bias0)        (MLP1; gate = gate_f per out col)
// MODE 2: out fp32 = res + acc + bias0                (proj / MLP2; hgate: skip zero K-blocks)
// TM=128: 4 waves 2x2 of 64x64 (16 MFMA/iter/wave); TM=64: 2x2 of 32x64 (8 MFMA/iter/wave).
template <int MODE, int TM>
__global__ __launch_bounds__(256) void gemm_kernel(
    const _Float16* __restrict__ A,
    const _Float16* __restrict__ W,
    const float* __restrict__ bias0,
    const float* __restrict__ bias1,
    const float* __restrict__ bias2,
    const float* __restrict__ res,
    const float* __restrict__ gate,
    const float* __restrict__ hgate,
    void* __restrict__ out0,
    void* __restrict__ out1,
    void* __restrict__ out2,
    int M, int N, int K)
{
    constexpr int MI = TM / 32;        // acc tiles along M per wave
    constexpr int AISS = TM / 64;      // global_load_lds issues for A tile
    int m0 = blockIdx.y * TM, n0 = blockIdx.x * 128;
    int seg = 0, segc0 = n0;
    if (MODE == 0) {
        seg = n0 / 768; segc0 = n0 - seg * 768;
        int h0 = segc0 >> 6;   // 128 cols = 2 heads
        if (hgate[h0] <= 0.0f && hgate[h0 + 1] <= 0.0f) return;  // outputs never read
    }
    __shared__ _Float16 As[TM * 32];    // row stride 32 halfs (64B); swizzle in global addr
    __shared__ _Float16 Bs[128 * 32];
    int t = threadIdx.x;
    int lane = t & 63, w = t >> 6;
    int wm = (w >> 1) * (TM / 2), wn = (w & 1) * 64;
    int L = lane & 15, quad = lane >> 4;
    int rchunk = (quad ^ ((L >> 2) & 3)) * 8;   // swizzled k-chunk for fragment reads

    floatx4 acc[MI][4];
    #pragma unroll
    for (int i = 0; i < MI; i++)
        #pragma unroll
        for (int j = 0; j < 4; j++)
            acc[i][j] = (floatx4){0.f, 0.f, 0.f, 0.f};

    // staging: physical chunk pc = issue*256 + t; row = pc>>2, kc = (pc&3) ^ ((pc>>4)&3)
    const _Float16* agp[AISS];
    const _Float16* bgp[2];
    #pragma unroll
    for (int i = 0; i < AISS; i++) {
        int pc = i * 256 + t;
        int row = pc >> 2;
        int kc = (pc & 3) ^ ((pc >> 4) & 3);
        agp[i] = A + (size_t)(m0 + row) * K + kc * 8;
    }
    #pragma unroll
    for (int i = 0; i < 2; i++) {
        int pc = i * 256 + t;
        int row = pc >> 2;
        int kc = (pc & 3) ^ ((pc >> 4) & 3);
        bgp[i] = W + (size_t)(n0 + row) * K + kc * 8;
    }
    unsigned wb = (unsigned)w * 512;   // wave-uniform LDS base (halfs) per issue block

    for (int k0 = 0; k0 < K; k0 += 32) {
        if (MODE == 2 && hgate && hgate[k0 >> 6] <= 0.0f) continue;  // A cols exactly zero
        __syncthreads();
        #pragma unroll
        for (int i = 0; i < AISS; i++) GLOAD_LDS(agp[i] + k0, As + i * 2048 + wb);
        #pragma unroll
        for (int i = 0; i < 2; i++)    GLOAD_LDS(bgp[i] + k0, Bs + i * 2048 + wb);
        __syncthreads();
        half8 af[MI], bf[4];
        #pragma unroll
        for (int i = 0; i < MI; i++) af[i] = *(const half8*)&As[(wm + i * 16 + L) * 32 + rchunk];
        #pragma unroll
        for (int j = 0; j < 4; j++)  bf[j] = *(const half8*)&Bs[(wn + j * 16 + L) * 32 + rchunk];
        #pragma unroll
        for (int i = 0; i < MI; i++)
            #pragma unroll
            for (int j = 0; j < 4; j++)
                acc[i][j] = __builtin_amdgcn_mfma_f32_16x16x32_f16(af[i], bf[j], acc[i][j], 0, 0, 0);
    }

    // epilogue: C row = quad*4 + r (M side), col = L (N side)  [verified m89/m91 layout]
    #pragma unroll
    for (int i = 0; i < MI; i++) {
        #pragma unroll
        for (int j = 0; j < 4; j++) {
            int gn = n0 + wn + j * 16 + L;
            if (MODE == 0) {
                int col = gn - seg * 768;
                const float* bsel = (seg == 0) ? bias0 : (seg == 1) ? bias1 : bias2;
                float bs = bsel[col];
                if (seg < 2) {
                    _Float16* o = (_Float16*)((seg == 0) ? out0 : out1);
                    #pragma unroll
                    for (int r = 0; r < 4; r++) {
                        int gm = m0 + wm + i * 16 + quad * 4 + r;
                        o[(size_t)gm * CC + col] = (_Float16)(acc[i][j][r] + bs);
                    }
                } else {
                    int gm0 = m0 + wm + i * 16 + quad * 4;
                    int b_ = gm0 >> 10, n_ = gm0 & 1023;
                    half4 pk;
                    #pragma unroll
                    for (int r = 0; r < 4; r++) pk[r] = (_Float16)(acc[i][j][r] + bs);
                    size_t idx = ((size_t)(b_ * HH + (col >> 6)) * 64 + (col & 63)) * NNN + n_;
                    *(half4*)&((_Float16*)out2)[idx] = pk;
                }
            } else {
                float bs = bias0[gn];
                #pragma unroll
                for (int r = 0; r < 4; r++) {
                    int gm = m0 + wm + i * 16 + quad * 4 + r;
                    float v = acc[i][j][r] + bs;
                    size_t idx = (size_t)gm * N + gn;
                    if (MODE == 1) {
                        float vv = (gate[gn] > 0.0f) ? 0.5f * v * (1.0f + erff(v * 0.70710678118f)) : 0.0f;
                        ((_Float16*)out0)[idx] = (_Float16)vv;
                    } else {
                        ((float*)out0)[idx] = res[idx] + v;
                    }
                }
            }
        }
    }
}

// ---------------- MFMA flash attention ----------------
__global__ __launch_bounds__(256) void attn_kernel(
    const _Float16* __restrict__ Q,    // [b][n][h*64+d]
    const _Float16* __restrict__ Kp,   // [b][n][h*64+d]
    const _Float16* __restrict__ Vt,   // [(b*H+h)*64+d][n]
    const float* __restrict__ gate_h,
    _Float16* __restrict__ Y)          // [b][n][h*64+d]
{
    int qt = blockIdx.x;
    int h  = blockIdx.y;
    int b  = blockIdx.z;
    int t = threadIdx.x;
    int q0 = qt * 64;
    size_t ybase = ((size_t)b * NNN + q0) * CC + h * DD;

    if (gate_h[h] <= 0.0f) {
        int r = t >> 2, c = (t & 3) * 16;
        half8 z = {(_Float16)0, (_Float16)0, (_Float16)0, (_Float16)0,
                   (_Float16)0, (_Float16)0, (_Float16)0, (_Float16)0};
        *(half8*)&Y[ybase + (size_t)r * CC + c]     = z;
        *(half8*)&Y[ybase + (size_t)r * CC + c + 8] = z;
        return;
    }

    __shared__ _Float16 Qs[64][72];
    __shared__ _Float16 Ks[64][72];
    __shared__ _Float16 Vs[64][72];   // Vs[d][key]
    __shared__ _Float16 Ps[64][72];

    int lane = t & 63, w = t >> 6;
    int L = lane & 15, quad = lane >> 4;

    {   // stage Q tile, pre-scaled by D^-0.5 = 0.125 (exact in fp16)
        int r = t >> 2, c = (t & 3) * 16;
        const half8* src = (const half8*)(Q + ((size_t)b * NNN + q0 + r) * CC + h * DD + c);
        half8 h0 = src[0], h1 = src[1];
        #pragma unroll
        for (int e = 0; e < 8; e++) { h0[e] = h0[e] * (_Float16)0.125f; h1[e] = h1[e] * (_Float16)0.125f; }
        *(half8*)&Qs[r][c]     = h0;
        *(half8*)&Qs[r][c + 8] = h1;
    }

    floatx4 O[4];
    float m_[4], l_[4];
    #pragma unroll
    for (int i = 0; i < 4; i++) { O[i] = (floatx4){0.f,0.f,0.f,0.f}; m_[i] = -1e30f; l_[i] = 0.0f; }

    const size_t kbase = (size_t)b * NNN * CC + h * DD;
    const size_t vbase = (size_t)(b * HH + h) * DD * NNN;

    for (int kt = 0; kt < 16; ++kt) {
        int k0 = kt * 64;
        __syncthreads();
        {
            int r = t >> 2, c = (t & 3) * 16;
            const half8* ks = (const half8*)(Kp + kbase + (size_t)(k0 + r) * CC + c);
            half8 ka = ks[0], kb = ks[1];
            *(half8*)&Ks[r][c]     = ka;
            *(half8*)&Ks[r][c + 8] = kb;
            const half8* vs = (const half8*)(Vt + vbase + (size_t)r * NNN + k0 + c);
            half8 va = vs[0], vb = vs[1];
            *(half8*)&Vs[r][c]     = va;
            *(half8*)&Vs[r][c + 8] = vb;
        }
        __syncthreads();

        half8 aq0 = *(const half8*)&Qs[16 * w + L][quad * 8];
        half8 aq1 = *(const half8*)&Qs[16 * w + L][quad * 8 + 32];
        floatx4 s[4];
        #pragma unroll
        for (int j = 0; j < 4; j++) {
            half8 b0 = *(const half8*)&Ks[16 * j + L][quad * 8];
            half8 b1 = *(const half8*)&Ks[16 * j + L][quad * 8 + 32];
            floatx4 z = (floatx4){0.f,0.f,0.f,0.f};
            z = __builtin_amdgcn_mfma_f32_16x16x32_f16(aq0, b0, z, 0, 0, 0);
            z = __builtin_amdgcn_mfma_f32_16x16x32_f16(aq1, b1, z, 0, 0, 0);
            s[j] = z;
        }

        #pragma unroll
        for (int r = 0; r < 4; r++) {
            float mx = fmaxf(fmaxf(s[0][r], s[1][r]), fmaxf(s[2][r], s[3][r]));
            mx = fmaxf(mx, __shfl_xor(mx, 1, 64));
            mx = fmaxf(mx, __shfl_xor(mx, 2, 64));
            mx = fmaxf(mx, __shfl_xor(mx, 4, 64));
            mx = fmaxf(mx, __shfl_xor(mx, 8, 64));
            float mnew = fmaxf(m_[r], mx);
            float alpha = __expf(m_[r] - mnew);
            m_[r] = mnew;
            float ps = 0.0f;
            #pragma unroll
            for (int j = 0; j < 4; j++) {
                float p = __expf(s[j][r] - mnew);
                s[j][r] = p; ps += p;
                Ps[16 * w + quad * 4 + r][L + 16 * j] = (_Float16)p;
            }
            ps += __shfl_xor(ps, 1, 64);
            ps += __shfl_xor(ps, 2, 64);
            ps += __shfl_xor(ps, 4, 64);
            ps += __shfl_xor(ps, 8, 64);
            l_[r] = l_[r] * alpha + ps;
            #pragma unroll
            for (int t4 = 0; t4 < 4; t4++) O[t4][r] *= alpha;
        }
        __syncthreads();

        half8 ap0 = *(const half8*)&Ps[16 * w + L][quad * 8];
        half8 ap1 = *(const half8*)&Ps[16 * w + L][quad * 8 + 32];
        #pragma unroll
        for (int t4 = 0; t4 < 4; t4++) {
            half8 b0 = *(const half8*)&Vs[16 * t4 + L][quad * 8];
            half8 b1 = *(const half8*)&Vs[16 * t4 + L][quad * 8 + 32];
            O[t4] = __builtin_amdgcn_mfma_f32_16x16x32_f16(ap0, b0, O[t4], 0, 0, 0);
            O[t4] = __builtin_amdgcn_mfma_f32_16x16x32_f16(ap1, b1, O[t4], 0, 0, 0);
        }
    }

    __syncthreads();
    #pragma unroll
    for (int r = 0; r < 4; r++) {
        float inv = 1.0f / l_[r];
        #pragma unroll
        for (int t4 = 0; t4 < 4; t4++)
            Ps[16 * w + quad * 4 + r][16 * t4 + L] = (_Float16)(O[t4][r] * inv);
    }
    __syncthreads();
    {
        int r = t >> 2, c = (t & 3) * 16;
        half8 o0 = *(const half8*)&Ps[r][c];
        half8 o1 = *(const half8*)&Ps[r][c + 8];
        *(half8*)&Y[ybase + (size_t)r * CC + c]     = o0;
        *(half8*)&Y[ybase + (size_t)r * CC + c + 8] = o1;
    }
}

// ---------------- launch ----------------
extern "C" void kernel_launch(void* const* d_in, const int* in_sizes, int n_in,
                              void* d_out, int out_size, void* d_ws, size_t ws_size,
                              hipStream_t stream)
{
    const float* x      = (const float*)d_in[0];
    const float* ln1_g  = (const float*)d_in[1];
    const float* ln1_b  = (const float*)d_in[2];
    const float* wq     = (const float*)d_in[3];
    const float* bq     = (const float*)d_in[4];
    const float* wk     = (const float*)d_in[5];
    const float* bk     = (const float*)d_in[6];
    const float* wv     = (const float*)d_in[7];
    const float* bv     = (const float*)d_in[8];
    const float* wp     = (const float*)d_in[9];
    const float* bp     = (const float*)d_in[10];
    const float* ln2_g  = (const float*)d_in[11];
    const float* ln2_b  = (const float*)d_in[12];
    const float* w1     = (const float*)d_in[13];
    const float* b1     = (const float*)d_in[14];
    const float* w2     = (const float*)d_in[15];
    const float* b2     = (const float*)d_in[16];
    const float* gate_h = (const float*)d_in[17];
    const float* gate_f = (const float*)d_in[18];

    char* ws = (char*)d_ws;
    _Float16* WQKVh = (_Float16*)(ws + 0);        // 2304x768 fp16 = 3538944 B (wq|wk|wv)
    _Float16* WPh = (_Float16*)(ws + 3538944);
    _Float16* W1h = (_Float16*)(ws + 4718592);
    _Float16* W2h = (_Float16*)(ws + 9437184);
    _Float16* XN  = (_Float16*)(ws + 14155776);
    _Float16* Qb  = (_Float16*)(ws + 39321600);
    _Float16* Kb  = (_Float16*)(ws + 64487424);
    _Float16* Vtb = (_Float16*)(ws + 89653248);   // V transposed: [(b*H+h)*64+d][n]
    _Float16* Yb  = (_Float16*)(ws + 114819072);
    float*    X1  = (float*)   (ws + 139984896);
    _Float16* XN2 = (_Float16*)(ws + 190316544);
    _Float16* F1  = (_Float16*)(ws + 14155776);  // aliases XN/Q/K (dead by then)

    // weight converts (QKV concatenated row-wise into one [2304][768] buffer)
    cvt_kernel<<<576, 256, 0, stream>>>(wq, WQKVh, 147456);
    cvt_kernel<<<576, 256, 0, stream>>>(wk, WQKVh + 589824, 147456);
    cvt_kernel<<<576, 256, 0, stream>>>(wv, WQKVh + 1179648, 147456);
    cvt_kernel<<<576, 256, 0, stream>>>(wp, WPh, 147456);
    cvt_kernel<<<2304, 256, 0, stream>>>(w1, W1h, 589824);
    cvt_kernel<<<2304, 256, 0, stream>>>(w2, W2h, 589824);

    // LN1
    ln_kernel<<<ROWS, 256, 0, stream>>>(x, ln1_g, ln1_b, XN);

    // merged QKV projection: N=2304, 2304 blocks (9/CU)
    gemm_kernel<0, 128><<<dim3(18, 128), 256, 0, stream>>>(
        XN, WQKVh, bq, bk, bv, nullptr, nullptr, gate_h, Qb, Kb, Vtb, ROWS, 2304, CC);

    // attention (MFMA, head-masked)
    attn_kernel<<<dim3(16, HH, BB), 256, 0, stream>>>(Qb, Kb, Vtb, gate_h, Yb);

    // proj + residual -> X1 (fp32); TM=64 -> 1536 blocks; masked-head K-blocks skipped
    gemm_kernel<2, 64><<<dim3(6, 256), 256, 0, stream>>>(
        Yb, WPh, bp, nullptr, nullptr, x, nullptr, gate_h, X1, nullptr, nullptr, ROWS, CC, CC);

    // LN2
    ln_kernel<<<ROWS, 256, 0, stream>>>(X1, ln2_g, ln2_b, XN2);

    // MLP1: gelu-gated -> F1 fp16 (3072 blocks, residency already fine)
    gemm_kernel<1, 128><<<dim3(24, 128), 256, 0, stream>>>(
        XN2, W1h, b1, nullptr, nullptr, nullptr, gate_f, nullptr, F1, nullptr, nullptr, ROWS, HIDN, CC);

    // MLP2 + residual -> out fp32; TM=64 -> 1536 blocks
    gemm_kernel<2, 64><<<dim3(6, 256), 256, 0, stream>>>(
        F1, W2h, b2, nullptr, nullptr, X1, nullptr, nullptr, (float*)d_out, nullptr, nullptr, ROWS, CC, HIDN);
}

// Round 5
// 630.103 us; speedup vs baseline: 1.6615x; 1.0400x over previous
//
#include <hip/hip_runtime.h>

#define BB 16
#define NNN 1024
#define CC 768
#define HH 12
#define DD 64
#define HIDN 3072
#define ROWS (BB*NNN)   // 16384

typedef _Float16 half8 __attribute__((ext_vector_type(8)));
typedef _Float16 half4 __attribute__((ext_vector_type(4)));
typedef float floatx4 __attribute__((ext_vector_type(4)));

#define GLOAD_LDS(g, l) __builtin_amdgcn_global_load_lds( \
    (const __attribute__((address_space(1))) void*)(g),    \
    (__attribute__((address_space(3))) void*)(l), 16, 0, 0)

// raw barrier: compiler memory fence but NO s_waitcnt vmcnt(0) drain
#define RAW_BARRIER() do { asm volatile("" ::: "memory"); \
    __builtin_amdgcn_s_barrier(); asm volatile("" ::: "memory"); } while (0)
// wait until <= n vector-memory ops outstanding (exp/lgkm unmasked)
#define VMCNT_WAIT(n) __builtin_amdgcn_s_waitcnt((n) | 0x0F70)

// ---------------- weight fp32 -> fp16 convert ----------------
__global__ void cvt_kernel(const float* __restrict__ src, _Float16* __restrict__ dst, int n4) {
    int i = blockIdx.x * blockDim.x + threadIdx.x;
    if (i < n4) {
        floatx4 v = ((const floatx4*)src)[i];
        half4 h;
        h[0] = (_Float16)v[0]; h[1] = (_Float16)v[1];
        h[2] = (_Float16)v[2]; h[3] = (_Float16)v[3];
        ((half4*)dst)[i] = h;
    }
}

// ---------------- LayerNorm (row of 768), fp32 in -> fp16 out ----------------
__global__ __launch_bounds__(256) void ln_kernel(const float* __restrict__ x,
                                                 const float* __restrict__ g,
                                                 const float* __restrict__ b,
                                                 _Float16* __restrict__ out) {
    int row = blockIdx.x;
    int t = threadIdx.x;
    const float* xr = x + (size_t)row * CC;
    float v0 = xr[t], v1 = xr[t + 256], v2 = xr[t + 512];
    float s = v0 + v1 + v2;
    float q = v0 * v0 + v1 * v1 + v2 * v2;
    #pragma unroll
    for (int m = 1; m < 64; m <<= 1) {
        s += __shfl_xor(s, m, 64);
        q += __shfl_xor(q, m, 64);
    }
    __shared__ float red[8];
    int wv = t >> 6, lane = t & 63;
    if (lane == 0) { red[wv] = s; red[wv + 4] = q; }
    __syncthreads();
    s = red[0] + red[1] + red[2] + red[3];
    q = red[4] + red[5] + red[6] + red[7];
    float mean = s * (1.0f / CC);
    float var = q * (1.0f / CC) - mean * mean;
    float rs = rsqrtf(var + 1e-5f);
    _Float16* orow = out + (size_t)row * CC;
    orow[t]       = (_Float16)((v0 - mean) * rs * g[t]       + b[t]);
    orow[t + 256] = (_Float16)((v1 - mean) * rs * g[t + 256] + b[t + 256]);
    orow[t + 512] = (_Float16)((v2 - mean) * rs * g[t + 512] + b[t + 512]);
}

// ---------------- MFMA GEMM, software-pipelined K-loop ----------------
// Double-buffered LDS; prefetch next tile via global_load_lds BEFORE waiting on the
// current tile with vmcnt(NISS); raw s_barrier (no vmcnt(0) drain) between waves.
// MODE 0: merged QKV (N=2304, segment routes epilogue; hgate skips masked head pairs)
// MODE 1: out fp16 = fmask * gelu(acc + bias0)   (MLP1)
// MODE 2: out fp32 = res + acc + bias0           (proj / MLP2; kmask skips zero K-blocks)
template <int MODE, int TM>
__global__ __launch_bounds__(256) void gemm_kernel(
    const _Float16* __restrict__ A,
    const _Float16* __restrict__ W,
    const float* __restrict__ bias0,
    const float* __restrict__ bias1,
    const float* __restrict__ bias2,
    const float* __restrict__ res,
    const float* __restrict__ gate,
    const float* __restrict__ hgate,
    void* __restrict__ out0,
    void* __restrict__ out1,
    void* __restrict__ out2,
    int M, int N, int K)
{
    constexpr int MI = TM / 32;        // acc tiles along M per wave
    constexpr int AISS = TM / 64;      // A-tile global_load_lds issues per thread
    constexpr int NISS = AISS + 2;     // total issues per thread per stage
    int m0 = blockIdx.y * TM, n0 = blockIdx.x * 128;
    int seg = 0;
    if (MODE == 0) {
        seg = n0 / 768;
        int segc0 = n0 - seg * 768;
        int h0 = segc0 >> 6;   // 128 cols = 2 heads
        if (hgate[h0] <= 0.0f && hgate[h0 + 1] <= 0.0f) return;  // outputs never read
    }
    // K-block gate mask (proj: zero A-columns from masked heads)
    unsigned kmask = 0xFFFFFFFFu;
    if (MODE == 2 && hgate) {
        kmask = 0;
        for (int i = 0; i < HH; i++) kmask |= (hgate[i] > 0.0f ? 1u : 0u) << i;
    }

    __shared__ _Float16 As[2][TM * 32];    // row stride 32 halfs; swizzle in global addr
    __shared__ _Float16 Bs[2][128 * 32];
    int t = threadIdx.x;
    int lane = t & 63, w = t >> 6;
    int wm = (w >> 1) * (TM / 2), wn = (w & 1) * 64;
    int L = lane & 15, quad = lane >> 4;
    int rchunk = (quad ^ ((L >> 2) & 3)) * 8;   // swizzled k-chunk for fragment reads

    floatx4 acc[MI][4];
    #pragma unroll
    for (int i = 0; i < MI; i++)
        #pragma unroll
        for (int j = 0; j < 4; j++)
            acc[i][j] = (floatx4){0.f, 0.f, 0.f, 0.f};

    // staging: physical chunk pc = issue*256 + t; row = pc>>2, kc = (pc&3) ^ ((pc>>4)&3)
    const _Float16* agp[AISS];
    const _Float16* bgp[2];
    #pragma unroll
    for (int i = 0; i < AISS; i++) {
        int pc = i * 256 + t;
        int row = pc >> 2;
        int kc = (pc & 3) ^ ((pc >> 4) & 3);
        agp[i] = A + (size_t)(m0 + row) * K + kc * 8;
    }
    #pragma unroll
    for (int i = 0; i < 2; i++) {
        int pc = i * 256 + t;
        int row = pc >> 2;
        int kc = (pc & 3) ^ ((pc >> 4) & 3);
        bgp[i] = W + (size_t)(n0 + row) * K + kc * 8;
    }
    unsigned wb = (unsigned)w * 512;   // wave-uniform LDS base (halfs) per issue block

    auto nextk = [&](int k0) -> int {
        if (MODE == 2)
            while (k0 < K && !((kmask >> ((k0 >> 6) & 31)) & 1)) k0 += 32;
        return k0;
    };
    auto stage = [&](int buf, int k0) {
        #pragma unroll
        for (int i = 0; i < AISS; i++) GLOAD_LDS(agp[i] + k0, &As[buf][i * 2048 + wb]);
        #pragma unroll
        for (int i = 0; i < 2; i++)    GLOAD_LDS(bgp[i] + k0, &Bs[buf][i * 2048 + wb]);
    };
    auto compute = [&](int buf) {
        half8 af[MI], bf[4];
        #pragma unroll
        for (int i = 0; i < MI; i++) af[i] = *(const half8*)&As[buf][(wm + i * 16 + L) * 32 + rchunk];
        #pragma unroll
        for (int j = 0; j < 4; j++)  bf[j] = *(const half8*)&Bs[buf][(wn + j * 16 + L) * 32 + rchunk];
        #pragma unroll
        for (int i = 0; i < MI; i++)
            #pragma unroll
            for (int j = 0; j < 4; j++)
                acc[i][j] = __builtin_amdgcn_mfma_f32_16x16x32_f16(af[i], bf[j], acc[i][j], 0, 0, 0);
    };

    int kc = nextk(0);
    if (kc < K) {
        stage(0, kc);
        int buf = 0;
        for (;;) {
            int kn = nextk(kc + 32);
            if (kn >= K) break;
            stage(buf ^ 1, kn);        // prefetch stays in flight across the barrier
            VMCNT_WAIT(NISS);          // only current tile's loads must have landed
            RAW_BARRIER();
            compute(buf);
            RAW_BARRIER();             // all waves done reading buf before restage
            buf ^= 1; kc = kn;
        }
        VMCNT_WAIT(0);                 // tail tile
        RAW_BARRIER();
        compute(buf);
    }

    // epilogue: C row = quad*4 + r (M side), col = L (N side)  [verified m89/m91 layout]
    #pragma unroll
    for (int i = 0; i < MI; i++) {
        #pragma unroll
        for (int j = 0; j < 4; j++) {
            int gn = n0 + wn + j * 16 + L;
            if (MODE == 0) {
                int col = gn - seg * 768;
                const float* bsel = (seg == 0) ? bias0 : (seg == 1) ? bias1 : bias2;
                float bs = bsel[col];
                if (seg < 2) {
                    _Float16* o = (_Float16*)((seg == 0) ? out0 : out1);
                    #pragma unroll
                    for (int r = 0; r < 4; r++) {
                        int gm = m0 + wm + i * 16 + quad * 4 + r;
                        o[(size_t)gm * CC + col] = (_Float16)(acc[i][j][r] + bs);
                    }
                } else {
                    int gm0 = m0 + wm + i * 16 + quad * 4;
                    int b_ = gm0 >> 10, n_ = gm0 & 1023;
                    half4 pk;
                    #pragma unroll
                    for (int r = 0; r < 4; r++) pk[r] = (_Float16)(acc[i][j][r] + bs);
                    size_t idx = ((size_t)(b_ * HH + (col >> 6)) * 64 + (col & 63)) * NNN + n_;
                    *(half4*)&((_Float16*)out2)[idx] = pk;
                }
            } else {
                float bs = bias0[gn];
                #pragma unroll
                for (int r = 0; r < 4; r++) {
                    int gm = m0 + wm + i * 16 + quad * 4 + r;
                    float v = acc[i][j][r] + bs;
                    size_t idx = (size_t)gm * N + gn;
                    if (MODE == 1) {
                        float vv = (gate[gn] > 0.0f) ? 0.5f * v * (1.0f + erff(v * 0.70710678118f)) : 0.0f;
                        ((_Float16*)out0)[idx] = (_Float16)vv;
                    } else {
                        ((float*)out0)[idx] = res[idx] + v;
                    }
                }
            }
        }
    }
}

// ---------------- MFMA flash attention ----------------
__global__ __launch_bounds__(256) void attn_kernel(
    const _Float16* __restrict__ Q,    // [b][n][h*64+d]
    const _Float16* __restrict__ Kp,   // [b][n][h*64+d]
    const _Float16* __restrict__ Vt,   // [(b*H+h)*64+d][n]
    const float* __restrict__ gate_h,
    _Float16* __restrict__ Y)          // [b][n][h*64+d]
{
    int qt = blockIdx.x;
    int h  = blockIdx.y;
    int b  = blockIdx.z;
    int t = threadIdx.x;
    int q0 = qt * 64;
    size_t ybase = ((size_t)b * NNN + q0) * CC + h * DD;

    if (gate_h[h] <= 0.0f) {
        int r = t >> 2, c = (t & 3) * 16;
        half8 z = {(_Float16)0, (_Float16)0, (_Float16)0, (_Float16)0,
                   (_Float16)0, (_Float16)0, (_Float16)0, (_Float16)0};
        *(half8*)&Y[ybase + (size_t)r * CC + c]     = z;
        *(half8*)&Y[ybase + (size_t)r * CC + c + 8] = z;
        return;
    }

    __shared__ _Float16 Qs[64][72];
    __shared__ _Float16 Ks[64][72];
    __shared__ _Float16 Vs[64][72];   // Vs[d][key]
    __shared__ _Float16 Ps[64][72];

    int lane = t & 63, w = t >> 6;
    int L = lane & 15, quad = lane >> 4;

    {   // stage Q tile, pre-scaled by D^-0.5 = 0.125 (exact in fp16)
        int r = t >> 2, c = (t & 3) * 16;
        const half8* src = (const half8*)(Q + ((size_t)b * NNN + q0 + r) * CC + h * DD + c);
        half8 h0 = src[0], h1 = src[1];
        #pragma unroll
        for (int e = 0; e < 8; e++) { h0[e] = h0[e] * (_Float16)0.125f; h1[e] = h1[e] * (_Float16)0.125f; }
        *(half8*)&Qs[r][c]     = h0;
        *(half8*)&Qs[r][c + 8] = h1;
    }

    floatx4 O[4];
    float m_[4], l_[4];
    #pragma unroll
    for (int i = 0; i < 4; i++) { O[i] = (floatx4){0.f,0.f,0.f,0.f}; m_[i] = -1e30f; l_[i] = 0.0f; }

    const size_t kbase = (size_t)b * NNN * CC + h * DD;
    const size_t vbase = (size_t)(b * HH + h) * DD * NNN;

    for (int kt = 0; kt < 16; ++kt) {
        int k0 = kt * 64;
        __syncthreads();
        {
            int r = t >> 2, c = (t & 3) * 16;
            const half8* ks = (const half8*)(Kp + kbase + (size_t)(k0 + r) * CC + c);
            half8 ka = ks[0], kb = ks[1];
            *(half8*)&Ks[r][c]     = ka;
            *(half8*)&Ks[r][c + 8] = kb;
            const half8* vs = (const half8*)(Vt + vbase + (size_t)r * NNN + k0 + c);
            half8 va = vs[0], vb = vs[1];
            *(half8*)&Vs[r][c]     = va;
            *(half8*)&Vs[r][c + 8] = vb;
        }
        __syncthreads();

        half8 aq0 = *(const half8*)&Qs[16 * w + L][quad * 8];
        half8 aq1 = *(const half8*)&Qs[16 * w + L][quad * 8 + 32];
        floatx4 s[4];
        #pragma unroll
        for (int j = 0; j < 4; j++) {
            half8 b0 = *(const half8*)&Ks[16 * j + L][quad * 8];
            half8 b1 = *(const half8*)&Ks[16 * j + L][quad * 8 + 32];
            floatx4 z = (floatx4){0.f,0.f,0.f,0.f};
            z = __builtin_amdgcn_mfma_f32_16x16x32_f16(aq0, b0, z, 0, 0, 0);
            z = __builtin_amdgcn_mfma_f32_16x16x32_f16(aq1, b1, z, 0, 0, 0);
            s[j] = z;
        }

        #pragma unroll
        for (int r = 0; r < 4; r++) {
            float mx = fmaxf(fmaxf(s[0][r], s[1][r]), fmaxf(s[2][r], s[3][r]));
            mx = fmaxf(mx, __shfl_xor(mx, 1, 64));
            mx = fmaxf(mx, __shfl_xor(mx, 2, 64));
            mx = fmaxf(mx, __shfl_xor(mx, 4, 64));
            mx = fmaxf(mx, __shfl_xor(mx, 8, 64));
            float mnew = fmaxf(m_[r], mx);
            float alpha = __expf(m_[r] - mnew);
            m_[r] = mnew;
            float ps = 0.0f;
            #pragma unroll
            for (int j = 0; j < 4; j++) {
                float p = __expf(s[j][r] - mnew);
                s[j][r] = p; ps += p;
                Ps[16 * w + quad * 4 + r][L + 16 * j] = (_Float16)p;
            }
            ps += __shfl_xor(ps, 1, 64);
            ps += __shfl_xor(ps, 2, 64);
            ps += __shfl_xor(ps, 4, 64);
            ps += __shfl_xor(ps, 8, 64);
            l_[r] = l_[r] * alpha + ps;
            #pragma unroll
            for (int t4 = 0; t4 < 4; t4++) O[t4][r] *= alpha;
        }
        __syncthreads();

        half8 ap0 = *(const half8*)&Ps[16 * w + L][quad * 8];
        half8 ap1 = *(const half8*)&Ps[16 * w + L][quad * 8 + 32];
        #pragma unroll
        for (int t4 = 0; t4 < 4; t4++) {
            half8 b0 = *(const half8*)&Vs[16 * t4 + L][quad * 8];
            half8 b1 = *(const half8*)&Vs[16 * t4 + L][quad * 8 + 32];
            O[t4] = __builtin_amdgcn_mfma_f32_16x16x32_f16(ap0, b0, O[t4], 0, 0, 0);
            O[t4] = __builtin_amdgcn_mfma_f32_16x16x32_f16(ap1, b1, O[t4], 0, 0, 0);
        }
    }

    __syncthreads();
    #pragma unroll
    for (int r = 0; r < 4; r++) {
        float inv = 1.0f / l_[r];
        #pragma unroll
        for (int t4 = 0; t4 < 4; t4++)
            Ps[16 * w + quad * 4 + r][16 * t4 + L] = (_Float16)(O[t4][r] * inv);
    }
    __syncthreads();
    {
        int r = t >> 2, c = (t & 3) * 16;
        half8 o0 = *(const half8*)&Ps[r][c];
        half8 o1 = *(const half8*)&Ps[r][c + 8];
        *(half8*)&Y[ybase + (size_t)r * CC + c]     = o0;
        *(half8*)&Y[ybase + (size_t)r * CC + c + 8] = o1;
    }
}

// ---------------- launch ----------------
extern "C" void kernel_launch(void* const* d_in, const int* in_sizes, int n_in,
                              void* d_out, int out_size, void* d_ws, size_t ws_size,
                              hipStream_t stream)
{
    const float* x      = (const float*)d_in[0];
    const float* ln1_g  = (const float*)d_in[1];
    const float* ln1_b  = (const float*)d_in[2];
    const float* wq     = (const float*)d_in[3];
    const float* bq     = (const float*)d_in[4];
    const float* wk     = (const float*)d_in[5];
    const float* bk     = (const float*)d_in[6];
    const float* wv     = (const float*)d_in[7];
    const float* bv     = (const float*)d_in[8];
    const float* wp     = (const float*)d_in[9];
    const float* bp     = (const float*)d_in[10];
    const float* ln2_g  = (const float*)d_in[11];
    const float* ln2_b  = (const float*)d_in[12];
    const float* w1     = (const float*)d_in[13];
    const float* b1     = (const float*)d_in[14];
    const float* w2     = (const float*)d_in[15];
    const float* b2     = (const float*)d_in[16];
    const float* gate_h = (const float*)d_in[17];
    const float* gate_f = (const float*)d_in[18];

    char* ws = (char*)d_ws;
    _Float16* WQKVh = (_Float16*)(ws + 0);        // 2304x768 fp16 (wq|wk|wv)
    _Float16* WPh = (_Float16*)(ws + 3538944);
    _Float16* W1h = (_Float16*)(ws + 4718592);
    _Float16* W2h = (_Float16*)(ws + 9437184);
    _Float16* XN  = (_Float16*)(ws + 14155776);
    _Float16* Qb  = (_Float16*)(ws + 39321600);
    _Float16* Kb  = (_Float16*)(ws + 64487424);
    _Float16* Vtb = (_Float16*)(ws + 89653248);   // V transposed: [(b*H+h)*64+d][n]
    _Float16* Yb  = (_Float16*)(ws + 114819072);
    float*    X1  = (float*)   (ws + 139984896);
    _Float16* XN2 = (_Float16*)(ws + 190316544);
    _Float16* F1  = (_Float16*)(ws + 14155776);  // aliases XN/Q/K (dead by then)

    // weight converts (QKV concatenated row-wise into one [2304][768] buffer)
    cvt_kernel<<<576, 256, 0, stream>>>(wq, WQKVh, 147456);
    cvt_kernel<<<576, 256, 0, stream>>>(wk, WQKVh + 589824, 147456);
    cvt_kernel<<<576, 256, 0, stream>>>(wv, WQKVh + 1179648, 147456);
    cvt_kernel<<<576, 256, 0, stream>>>(wp, WPh, 147456);
    cvt_kernel<<<2304, 256, 0, stream>>>(w1, W1h, 589824);
    cvt_kernel<<<2304, 256, 0, stream>>>(w2, W2h, 589824);

    // LN1
    ln_kernel<<<ROWS, 256, 0, stream>>>(x, ln1_g, ln1_b, XN);

    // merged QKV projection: N=2304, 2304 blocks
    gemm_kernel<0, 128><<<dim3(18, 128), 256, 0, stream>>>(
        XN, WQKVh, bq, bk, bv, nullptr, nullptr, gate_h, Qb, Kb, Vtb, ROWS, 2304, CC);

    // attention (MFMA, head-masked)
    attn_kernel<<<dim3(16, HH, BB), 256, 0, stream>>>(Qb, Kb, Vtb, gate_h, Yb);

    // proj + residual -> X1 (fp32); masked-head K-blocks skipped via kmask
    gemm_kernel<2, 64><<<dim3(6, 256), 256, 0, stream>>>(
        Yb, WPh, bp, nullptr, nullptr, x, nullptr, gate_h, X1, nullptr, nullptr, ROWS, CC, CC);

    // LN2
    ln_kernel<<<ROWS, 256, 0, stream>>>(X1, ln2_g, ln2_b, XN2);

    // MLP1: gelu-gated -> F1 fp16
    gemm_kernel<1, 128><<<dim3(24, 128), 256, 0, stream>>>(
        XN2, W1h, b1, nullptr, nullptr, nullptr, gate_f, nullptr, F1, nullptr, nullptr, ROWS, HIDN, CC);

    // MLP2 + residual -> out fp32
    gemm_kernel<2, 64><<<dim3(6, 256), 256, 0, stream>>>(
        F1, W2h, b2, nullptr, nullptr, X1, nullptr, nullptr, (float*)d_out, nullptr, nullptr, ROWS, CC, HIDN);
}

// Round 6
// 613.865 us; speedup vs baseline: 1.7055x; 1.0265x over previous
//
#include <hip/hip_runtime.h>

#define BB 16
#define NNN 1024
#define CC 768
#define HH 12
#define DD 64
#define HIDN 3072
#define ROWS (BB*NNN)   // 16384

typedef _Float16 half8 __attribute__((ext_vector_type(8)));
typedef _Float16 half4 __attribute__((ext_vector_type(4)));
typedef float floatx4 __attribute__((ext_vector_type(4)));

#define GLOAD_LDS(g, l) __builtin_amdgcn_global_load_lds( \
    (const __attribute__((address_space(1))) void*)(g),    \
    (__attribute__((address_space(3))) void*)(l), 16, 0, 0)

// raw barrier: compiler memory fence but NO s_waitcnt vmcnt(0) drain
#define RAW_BARRIER() do { asm volatile("" ::: "memory"); \
    __builtin_amdgcn_s_barrier(); asm volatile("" ::: "memory"); } while (0)
// wait until <= n vector-memory ops outstanding (exp/lgkm unmasked)
#define VMCNT_WAIT(n) __builtin_amdgcn_s_waitcnt((n) | 0x0F70)

// ---------------- weight fp32 -> fp16 convert ----------------
__global__ void cvt_kernel(const float* __restrict__ src, _Float16* __restrict__ dst, int n4) {
    int i = blockIdx.x * blockDim.x + threadIdx.x;
    if (i < n4) {
        floatx4 v = ((const floatx4*)src)[i];
        half4 h;
        h[0] = (_Float16)v[0]; h[1] = (_Float16)v[1];
        h[2] = (_Float16)v[2]; h[3] = (_Float16)v[3];
        ((half4*)dst)[i] = h;
    }
}

// ---------------- LayerNorm (row of 768), fp32 in -> fp16 out ----------------
__global__ __launch_bounds__(256) void ln_kernel(const float* __restrict__ x,
                                                 const float* __restrict__ g,
                                                 const float* __restrict__ b,
                                                 _Float16* __restrict__ out) {
    int row = blockIdx.x;
    int t = threadIdx.x;
    const float* xr = x + (size_t)row * CC;
    float v0 = xr[t], v1 = xr[t + 256], v2 = xr[t + 512];
    float s = v0 + v1 + v2;
    float q = v0 * v0 + v1 * v1 + v2 * v2;
    #pragma unroll
    for (int m = 1; m < 64; m <<= 1) {
        s += __shfl_xor(s, m, 64);
        q += __shfl_xor(q, m, 64);
    }
    __shared__ float red[8];
    int wv = t >> 6, lane = t & 63;
    if (lane == 0) { red[wv] = s; red[wv + 4] = q; }
    __syncthreads();
    s = red[0] + red[1] + red[2] + red[3];
    q = red[4] + red[5] + red[6] + red[7];
    float mean = s * (1.0f / CC);
    float var = q * (1.0f / CC) - mean * mean;
    float rs = rsqrtf(var + 1e-5f);
    _Float16* orow = out + (size_t)row * CC;
    orow[t]       = (_Float16)((v0 - mean) * rs * g[t]       + b[t]);
    orow[t + 256] = (_Float16)((v1 - mean) * rs * g[t + 256] + b[t + 256]);
    orow[t + 512] = (_Float16)((v2 - mean) * rs * g[t + 512] + b[t + 512]);
}

// ---------------- MFMA GEMM, 3-stage pipelined K-loop + XCD-swizzled grid ------
// 1D grid; flat id f: xcd = f&7, slot = f>>3; m_stripe = xcd*(GM/8)+slot/GN,
// n_idx = slot%GN -> all N-blocks sharing an A-stripe run consecutively on ONE XCD
// (A-stripe fetched once into that XCD's L2).  Triple-buffered LDS: prefetch is
// issued 2 iterations ahead; steady-state waits vmcnt(2*NISS).
// MODE 0: merged QKV (N=2304, segment routes epilogue; hgate skips masked head pairs)
// MODE 1: out fp16 = fmask * gelu(acc + bias0)   (MLP1)
// MODE 2: out fp32 = res + acc + bias0           (proj / MLP2; kmask skips zero K-blocks)
template <int MODE, int TM>
__global__ __launch_bounds__(256) void gemm_kernel(
    const _Float16* __restrict__ A,
    const _Float16* __restrict__ W,
    const float* __restrict__ bias0,
    const float* __restrict__ bias1,
    const float* __restrict__ bias2,
    const float* __restrict__ res,
    const float* __restrict__ gate,
    const float* __restrict__ hgate,
    void* __restrict__ out0,
    void* __restrict__ out1,
    void* __restrict__ out2,
    int M, int N, int K)
{
    constexpr int MI = TM / 32;        // acc tiles along M per wave
    constexpr int AISS = TM / 64;      // A-tile global_load_lds issues per thread
    constexpr int NISS = AISS + 2;     // total issues per thread per stage
    // XCD-aware swizzle
    int GN = N >> 7, GM = M / TM;
    int f = blockIdx.x;
    int xcd = f & 7, slot = f >> 3;
    int m_idx = xcd * (GM >> 3) + slot / GN;
    int n_idx = slot - (slot / GN) * GN;
    int m0 = m_idx * TM, n0 = n_idx * 128;

    int seg = 0;
    if (MODE == 0) {
        seg = n0 / 768;
        int segc0 = n0 - seg * 768;
        int h0 = segc0 >> 6;   // 128 cols = 2 heads
        if (hgate[h0] <= 0.0f && hgate[h0 + 1] <= 0.0f) return;  // outputs never read
    }
    // K-block gate mask (proj: zero A-columns from masked heads)
    unsigned kmask = 0xFFFFFFFFu;
    if (MODE == 2 && hgate) {
        kmask = 0;
        for (int i = 0; i < HH; i++) kmask |= (hgate[i] > 0.0f ? 1u : 0u) << i;
    }

    __shared__ _Float16 As[3][TM * 32];    // row stride 32 halfs; swizzle in global addr
    __shared__ _Float16 Bs[3][128 * 32];
    int t = threadIdx.x;
    int lane = t & 63, w = t >> 6;
    int wm = (w >> 1) * (TM / 2), wn = (w & 1) * 64;
    int L = lane & 15, quad = lane >> 4;
    int rchunk = (quad ^ ((L >> 2) & 3)) * 8;   // swizzled k-chunk for fragment reads

    floatx4 acc[MI][4];
    #pragma unroll
    for (int i = 0; i < MI; i++)
        #pragma unroll
        for (int j = 0; j < 4; j++)
            acc[i][j] = (floatx4){0.f, 0.f, 0.f, 0.f};

    // staging: physical chunk pc = issue*256 + t; row = pc>>2, kc = (pc&3) ^ ((pc>>4)&3)
    const _Float16* agp[AISS];
    const _Float16* bgp[2];
    #pragma unroll
    for (int i = 0; i < AISS; i++) {
        int pc = i * 256 + t;
        int row = pc >> 2;
        int kc = (pc & 3) ^ ((pc >> 4) & 3);
        agp[i] = A + (size_t)(m0 + row) * K + kc * 8;
    }
    #pragma unroll
    for (int i = 0; i < 2; i++) {
        int pc = i * 256 + t;
        int row = pc >> 2;
        int kc = (pc & 3) ^ ((pc >> 4) & 3);
        bgp[i] = W + (size_t)(n0 + row) * K + kc * 8;
    }
    unsigned wb = (unsigned)w * 512;   // wave-uniform LDS base (halfs) per issue block

    auto nextk = [&](int k0) -> int {
        if (MODE == 2)
            while (k0 < K && !((kmask >> ((k0 >> 6) & 31)) & 1)) k0 += 32;
        return k0;
    };
    auto stage = [&](int buf, int k0) {
        #pragma unroll
        for (int i = 0; i < AISS; i++) GLOAD_LDS(agp[i] + k0, &As[buf][i * 2048 + wb]);
        #pragma unroll
        for (int i = 0; i < 2; i++)    GLOAD_LDS(bgp[i] + k0, &Bs[buf][i * 2048 + wb]);
    };
    auto compute = [&](int buf) {
        half8 af[MI], bf[4];
        #pragma unroll
        for (int i = 0; i < MI; i++) af[i] = *(const half8*)&As[buf][(wm + i * 16 + L) * 32 + rchunk];
        #pragma unroll
        for (int j = 0; j < 4; j++)  bf[j] = *(const half8*)&Bs[buf][(wn + j * 16 + L) * 32 + rchunk];
        #pragma unroll
        for (int i = 0; i < MI; i++)
            #pragma unroll
            for (int j = 0; j < 4; j++)
                acc[i][j] = __builtin_amdgcn_mfma_f32_16x16x32_f16(af[i], bf[j], acc[i][j], 0, 0, 0);
    };

    int kcur = nextk(0);
    if (kcur < K) {
        stage(0, kcur);
        int kn1 = nextk(kcur + 32);
        int kn2 = K;
        if (kn1 < K) { stage(1, kn1); kn2 = nextk(kn1 + 32); }
        int buf = 0;
        while (kn2 < K) {               // steady state: 2 stages in flight behind us
            int bnext = buf + 2; if (bnext >= 3) bnext -= 3;
            stage(bnext, kn2);
            VMCNT_WAIT(2 * NISS);       // current stage landed; 2 prefetches in flight
            RAW_BARRIER();
            compute(buf);
            RAW_BARRIER();              // all waves done reading buf before its restage
            buf = buf + 1; if (buf >= 3) buf -= 3;
            kcur = kn1; kn1 = kn2; kn2 = nextk(kn2 + 32);
        }
        if (kn1 < K) {                  // two tiles left
            VMCNT_WAIT(NISS);
            RAW_BARRIER();
            compute(buf);
            buf = buf + 1; if (buf >= 3) buf -= 3;
        }
        VMCNT_WAIT(0);                  // last tile
        RAW_BARRIER();
        compute(buf);
    }

    // epilogue: C row = quad*4 + r (M side), col = L (N side)  [verified m89/m91 layout]
    #pragma unroll
    for (int i = 0; i < MI; i++) {
        #pragma unroll
        for (int j = 0; j < 4; j++) {
            int gn = n0 + wn + j * 16 + L;
            if (MODE == 0) {
                int col = gn - seg * 768;
                const float* bsel = (seg == 0) ? bias0 : (seg == 1) ? bias1 : bias2;
                float bs = bsel[col];
                if (seg < 2) {
                    _Float16* o = (_Float16*)((seg == 0) ? out0 : out1);
                    #pragma unroll
                    for (int r = 0; r < 4; r++) {
                        int gm = m0 + wm + i * 16 + quad * 4 + r;
                        o[(size_t)gm * CC + col] = (_Float16)(acc[i][j][r] + bs);
                    }
                } else {
                    int gm0 = m0 + wm + i * 16 + quad * 4;
                    int b_ = gm0 >> 10, n_ = gm0 & 1023;
                    half4 pk;
                    #pragma unroll
                    for (int r = 0; r < 4; r++) pk[r] = (_Float16)(acc[i][j][r] + bs);
                    size_t idx = ((size_t)(b_ * HH + (col >> 6)) * 64 + (col & 63)) * NNN + n_;
                    *(half4*)&((_Float16*)out2)[idx] = pk;
                }
            } else {
                float bs = bias0[gn];
                #pragma unroll
                for (int r = 0; r < 4; r++) {
                    int gm = m0 + wm + i * 16 + quad * 4 + r;
                    float v = acc[i][j][r] + bs;
                    size_t idx = (size_t)gm * N + gn;
                    if (MODE == 1) {
                        float vv = (gate[gn] > 0.0f) ? 0.5f * v * (1.0f + erff(v * 0.70710678118f)) : 0.0f;
                        ((_Float16*)out0)[idx] = (_Float16)vv;
                    } else {
                        ((float*)out0)[idx] = res[idx] + v;
                    }
                }
            }
        }
    }
}

// ---------------- MFMA flash attention ----------------
__global__ __launch_bounds__(256) void attn_kernel(
    const _Float16* __restrict__ Q,    // [b][n][h*64+d]
    const _Float16* __restrict__ Kp,   // [b][n][h*64+d]
    const _Float16* __restrict__ Vt,   // [(b*H+h)*64+d][n]
    const float* __restrict__ gate_h,
    _Float16* __restrict__ Y)          // [b][n][h*64+d]
{
    int qt = blockIdx.x;
    int h  = blockIdx.y;
    int b  = blockIdx.z;
    int t = threadIdx.x;
    int q0 = qt * 64;
    size_t ybase = ((size_t)b * NNN + q0) * CC + h * DD;

    if (gate_h[h] <= 0.0f) {
        int r = t >> 2, c = (t & 3) * 16;
        half8 z = {(_Float16)0, (_Float16)0, (_Float16)0, (_Float16)0,
                   (_Float16)0, (_Float16)0, (_Float16)0, (_Float16)0};
        *(half8*)&Y[ybase + (size_t)r * CC + c]     = z;
        *(half8*)&Y[ybase + (size_t)r * CC + c + 8] = z;
        return;
    }

    __shared__ _Float16 Qs[64][72];
    __shared__ _Float16 Ks[64][72];
    __shared__ _Float16 Vs[64][72];   // Vs[d][key]
    __shared__ _Float16 Ps[64][72];

    int lane = t & 63, w = t >> 6;
    int L = lane & 15, quad = lane >> 4;

    {   // stage Q tile, pre-scaled by D^-0.5 = 0.125 (exact in fp16)
        int r = t >> 2, c = (t & 3) * 16;
        const half8* src = (const half8*)(Q + ((size_t)b * NNN + q0 + r) * CC + h * DD + c);
        half8 h0 = src[0], h1 = src[1];
        #pragma unroll
        for (int e = 0; e < 8; e++) { h0[e] = h0[e] * (_Float16)0.125f; h1[e] = h1[e] * (_Float16)0.125f; }
        *(half8*)&Qs[r][c]     = h0;
        *(half8*)&Qs[r][c + 8] = h1;
    }

    floatx4 O[4];
    float m_[4], l_[4];
    #pragma unroll
    for (int i = 0; i < 4; i++) { O[i] = (floatx4){0.f,0.f,0.f,0.f}; m_[i] = -1e30f; l_[i] = 0.0f; }

    const size_t kbase = (size_t)b * NNN * CC + h * DD;
    const size_t vbase = (size_t)(b * HH + h) * DD * NNN;

    for (int kt = 0; kt < 16; ++kt) {
        int k0 = kt * 64;
        __syncthreads();
        {
            int r = t >> 2, c = (t & 3) * 16;
            const half8* ks = (const half8*)(Kp + kbase + (size_t)(k0 + r) * CC + c);
            half8 ka = ks[0], kb = ks[1];
            *(half8*)&Ks[r][c]     = ka;
            *(half8*)&Ks[r][c + 8] = kb;
            const half8* vs = (const half8*)(Vt + vbase + (size_t)r * NNN + k0 + c);
            half8 va = vs[0], vb = vs[1];
            *(half8*)&Vs[r][c]     = va;
            *(half8*)&Vs[r][c + 8] = vb;
        }
        __syncthreads();

        half8 aq0 = *(const half8*)&Qs[16 * w + L][quad * 8];
        half8 aq1 = *(const half8*)&Qs[16 * w + L][quad * 8 + 32];
        floatx4 s[4];
        #pragma unroll
        for (int j = 0; j < 4; j++) {
            half8 b0 = *(const half8*)&Ks[16 * j + L][quad * 8];
            half8 b1 = *(const half8*)&Ks[16 * j + L][quad * 8 + 32];
            floatx4 z = (floatx4){0.f,0.f,0.f,0.f};
            z = __builtin_amdgcn_mfma_f32_16x16x32_f16(aq0, b0, z, 0, 0, 0);
            z = __builtin_amdgcn_mfma_f32_16x16x32_f16(aq1, b1, z, 0, 0, 0);
            s[j] = z;
        }

        #pragma unroll
        for (int r = 0; r < 4; r++) {
            float mx = fmaxf(fmaxf(s[0][r], s[1][r]), fmaxf(s[2][r], s[3][r]));
            mx = fmaxf(mx, __shfl_xor(mx, 1, 64));
            mx = fmaxf(mx, __shfl_xor(mx, 2, 64));
            mx = fmaxf(mx, __shfl_xor(mx, 4, 64));
            mx = fmaxf(mx, __shfl_xor(mx, 8, 64));
            float mnew = fmaxf(m_[r], mx);
            float alpha = __expf(m_[r] - mnew);
            m_[r] = mnew;
            float ps = 0.0f;
            #pragma unroll
            for (int j = 0; j < 4; j++) {
                float p = __expf(s[j][r] - mnew);
                s[j][r] = p; ps += p;
                Ps[16 * w + quad * 4 + r][L + 16 * j] = (_Float16)p;
            }
            ps += __shfl_xor(ps, 1, 64);
            ps += __shfl_xor(ps, 2, 64);
            ps += __shfl_xor(ps, 4, 64);
            ps += __shfl_xor(ps, 8, 64);
            l_[r] = l_[r] * alpha + ps;
            #pragma unroll
            for (int t4 = 0; t4 < 4; t4++) O[t4][r] *= alpha;
        }
        __syncthreads();

        half8 ap0 = *(const half8*)&Ps[16 * w + L][quad * 8];
        half8 ap1 = *(const half8*)&Ps[16 * w + L][quad * 8 + 32];
        #pragma unroll
        for (int t4 = 0; t4 < 4; t4++) {
            half8 b0 = *(const half8*)&Vs[16 * t4 + L][quad * 8];
            half8 b1 = *(const half8*)&Vs[16 * t4 + L][quad * 8 + 32];
            O[t4] = __builtin_amdgcn_mfma_f32_16x16x32_f16(ap0, b0, O[t4], 0, 0, 0);
            O[t4] = __builtin_amdgcn_mfma_f32_16x16x32_f16(ap1, b1, O[t4], 0, 0, 0);
        }
    }

    __syncthreads();
    #pragma unroll
    for (int r = 0; r < 4; r++) {
        float inv = 1.0f / l_[r];
        #pragma unroll
        for (int t4 = 0; t4 < 4; t4++)
            Ps[16 * w + quad * 4 + r][16 * t4 + L] = (_Float16)(O[t4][r] * inv);
    }
    __syncthreads();
    {
        int r = t >> 2, c = (t & 3) * 16;
        half8 o0 = *(const half8*)&Ps[r][c];
        half8 o1 = *(const half8*)&Ps[r][c + 8];
        *(half8*)&Y[ybase + (size_t)r * CC + c]     = o0;
        *(half8*)&Y[ybase + (size_t)r * CC + c + 8] = o1;
    }
}

// ---------------- launch ----------------
extern "C" void kernel_launch(void* const* d_in, const int* in_sizes, int n_in,
                              void* d_out, int out_size, void* d_ws, size_t ws_size,
                              hipStream_t stream)
{
    const float* x      = (const float*)d_in[0];
    const float* ln1_g  = (const float*)d_in[1];
    const float* ln1_b  = (const float*)d_in[2];
    const float* wq     = (const float*)d_in[3];
    const float* bq     = (const float*)d_in[4];
    const float* wk     = (const float*)d_in[5];
    const float* bk     = (const float*)d_in[6];
    const float* wv     = (const float*)d_in[7];
    const float* bv     = (const float*)d_in[8];
    const float* wp     = (const float*)d_in[9];
    const float* bp     = (const float*)d_in[10];
    const float* ln2_g  = (const float*)d_in[11];
    const float* ln2_b  = (const float*)d_in[12];
    const float* w1     = (const float*)d_in[13];
    const float* b1     = (const float*)d_in[14];
    const float* w2     = (const float*)d_in[15];
    const float* b2     = (const float*)d_in[16];
    const float* gate_h = (const float*)d_in[17];
    const float* gate_f = (const float*)d_in[18];

    char* ws = (char*)d_ws;
    _Float16* WQKVh = (_Float16*)(ws + 0);        // 2304x768 fp16 (wq|wk|wv)
    _Float16* WPh = (_Float16*)(ws + 3538944);
    _Float16* W1h = (_Float16*)(ws + 4718592);
    _Float16* W2h = (_Float16*)(ws + 9437184);
    _Float16* XN  = (_Float16*)(ws + 14155776);
    _Float16* Qb  = (_Float16*)(ws + 39321600);
    _Float16* Kb  = (_Float16*)(ws + 64487424);
    _Float16* Vtb = (_Float16*)(ws + 89653248);   // V transposed: [(b*H+h)*64+d][n]
    _Float16* Yb  = (_Float16*)(ws + 114819072);
    float*    X1  = (float*)   (ws + 139984896);
    _Float16* XN2 = (_Float16*)(ws + 190316544);
    _Float16* F1  = (_Float16*)(ws + 14155776);  // aliases XN/Q/K (dead by then)

    // weight converts (QKV concatenated row-wise into one [2304][768] buffer)
    cvt_kernel<<<576, 256, 0, stream>>>(wq, WQKVh, 147456);
    cvt_kernel<<<576, 256, 0, stream>>>(wk, WQKVh + 589824, 147456);
    cvt_kernel<<<576, 256, 0, stream>>>(wv, WQKVh + 1179648, 147456);
    cvt_kernel<<<576, 256, 0, stream>>>(wp, WPh, 147456);
    cvt_kernel<<<2304, 256, 0, stream>>>(w1, W1h, 589824);
    cvt_kernel<<<2304, 256, 0, stream>>>(w2, W2h, 589824);

    // LN1
    ln_kernel<<<ROWS, 256, 0, stream>>>(x, ln1_g, ln1_b, XN);

    // merged QKV projection: N=2304 (18 n-blocks/stripe share one XCD's L2)
    gemm_kernel<0, 128><<<2304, 256, 0, stream>>>(
        XN, WQKVh, bq, bk, bv, nullptr, nullptr, gate_h, Qb, Kb, Vtb, ROWS, 2304, CC);

    // attention (MFMA, head-masked)
    attn_kernel<<<dim3(16, HH, BB), 256, 0, stream>>>(Qb, Kb, Vtb, gate_h, Yb);

    // proj + residual -> X1 (fp32); masked-head K-blocks skipped via kmask
    gemm_kernel<2, 64><<<1536, 256, 0, stream>>>(
        Yb, WPh, bp, nullptr, nullptr, x, nullptr, gate_h, X1, nullptr, nullptr, ROWS, CC, CC);

    // LN2
    ln_kernel<<<ROWS, 256, 0, stream>>>(X1, ln2_g, ln2_b, XN2);

    // MLP1: gelu-gated -> F1 fp16
    gemm_kernel<1, 128><<<3072, 256, 0, stream>>>(
        XN2, W1h, b1, nullptr, nullptr, nullptr, gate_f, nullptr, F1, nullptr, nullptr, ROWS, HIDN, CC);

    // MLP2 + residual -> out fp32
    gemm_kernel<2, 64><<<1536, 256, 0, stream>>>(
        F1, W2h, b2, nullptr, nullptr, X1, nullptr, nullptr, (float*)d_out, nullptr, nullptr, ROWS, CC, HIDN);
}